// Round 2
// baseline (2909.979 us; speedup 1.0000x reference)
//
#include <hip/hip_runtime.h>

#define HID 256
#define EF  64
#define KIN 320      // HID + EF
#define NC  4096
#define NE  65536
#define BSZ 4
#define EPSV 1e-5f

// edge kernel tiling
#define ME   16      // edges per block: LDS ~20.9KB -> 7 blocks/CU (was 32 -> 3 blocks/CU)
#define XSTR 324     // LDS stride for X tile (floats), 16B-aligned, breaks bank pow2
#define HSTR 260     // LDS stride for hidden tile
// node kernel tiling
#define MN    16     // rows per block
#define XSTR2 516    // LDS stride for [cell_x | agg] tile

// pick float4 component with constant index (folds after unroll)
#define F4C(v, kk) ((kk) == 0 ? (v).x : (kk) == 1 ? (v).y : (kk) == 2 ? (v).z : (v).w)

__global__ void zero_kernel(float4* __restrict__ p, int n4) {
    int i = blockIdx.x * blockDim.x + threadIdx.x;
    int stride = gridDim.x * blockDim.x;
    float4 z = make_float4(0.f, 0.f, 0.f, 0.f);
    for (; i < n4; i += stride) p[i] = z;
}

__global__ __launch_bounds__(256)
void count_kernel(const int* __restrict__ eidx, float* __restrict__ counts) {
    int g = blockIdx.x * 256 + threadIdx.x;     // g in [0, BSZ*NE)
    int d = eidx[(size_t)g * 2 + 1];
    d = min(max(d, 0), NC - 1);
    int b = g >> 16;                            // NE = 65536
    atomicAdd(&counts[b * NC + d], 1.0f);
}

// 16 edges/block, 256 threads: tn=tid&31 (8 cols each), tm=tid>>5 (8 groups x 2 rows)
__global__ __launch_bounds__(256, 7)
void edge_kernel(const float* __restrict__ cell_x,
                 const int*   __restrict__ eidx,
                 const float* __restrict__ eattr,
                 const float* __restrict__ W1, const float* __restrict__ b1,
                 const float* __restrict__ W2, const float* __restrict__ b2,
                 float* __restrict__ agg) {
    __shared__ float xs[ME * XSTR];   // X tile; later reused for hidden tile
    __shared__ int s_src[ME], s_dst[ME];

    const int tid = threadIdx.x;
    const int b   = blockIdx.x >> 12;            // 4096 blocks per batch
    const int e0  = (blockIdx.x & 4095) * ME;

    if (tid < ME) {
        int2 v = ((const int2*)eidx)[(size_t)b * NE + e0 + tid];
        s_src[tid] = min(max(v.x, 0), NC - 1);
        s_dst[tid] = min(max(v.y, 0), NC - 1);
    }
    __syncthreads();

    // gather X = [src_x | edge_attr]: wave wv loads edges wv*4 .. wv*4+3
    const int wv = tid >> 6, ln = tid & 63;
    #pragma unroll
    for (int i = 0; i < 4; ++i) {
        int m = wv * 4 + i;
        const float4* crow = (const float4*)(cell_x + ((size_t)b * NC + s_src[m]) * HID);
        ((float4*)&xs[m * XSTR])[ln] = crow[ln];                 // 64 lanes * 4 = 256 floats
        if (ln < 16) {
            const float4* arow = (const float4*)(eattr + ((size_t)b * NE + e0 + m) * EF);
            ((float4*)&xs[m * XSTR + HID])[ln] = arow[ln];       // 64 floats
        }
    }
    __syncthreads();

    const int tn = tid & 31, tm = tid >> 5;      // 32 col-groups x 8 row-groups (2 rows each)
    // ---- GEMM1: hidden = relu(X @ W1 + b1), K=320 ----
    float acc[2][8];
    #pragma unroll
    for (int mi = 0; mi < 2; ++mi)
        #pragma unroll
        for (int ni = 0; ni < 8; ++ni)
            acc[mi][ni] = b1[tn * 8 + ni];

    for (int k0 = 0; k0 < KIN; k0 += 4) {
        float4 a4[2];
        #pragma unroll
        for (int mi = 0; mi < 2; ++mi)
            a4[mi] = *(const float4*)&xs[(tm * 2 + mi) * XSTR + k0];
        #pragma unroll
        for (int kk = 0; kk < 4; ++kk) {
            float4 w0 = *(const float4*)&W1[(size_t)(k0 + kk) * HID + tn * 8];
            float4 w1 = *(const float4*)&W1[(size_t)(k0 + kk) * HID + tn * 8 + 4];
            #pragma unroll
            for (int mi = 0; mi < 2; ++mi) {
                float a = F4C(a4[mi], kk);
                acc[mi][0] = fmaf(a, w0.x, acc[mi][0]);
                acc[mi][1] = fmaf(a, w0.y, acc[mi][1]);
                acc[mi][2] = fmaf(a, w0.z, acc[mi][2]);
                acc[mi][3] = fmaf(a, w0.w, acc[mi][3]);
                acc[mi][4] = fmaf(a, w1.x, acc[mi][4]);
                acc[mi][5] = fmaf(a, w1.y, acc[mi][5]);
                acc[mi][6] = fmaf(a, w1.z, acc[mi][6]);
                acc[mi][7] = fmaf(a, w1.w, acc[mi][7]);
            }
        }
    }
    // relu + store hidden into LDS (reuse xs)
    __syncthreads();   // all X reads done before overwrite
    #pragma unroll
    for (int mi = 0; mi < 2; ++mi) {
        float4 h0 = make_float4(fmaxf(acc[mi][0], 0.f), fmaxf(acc[mi][1], 0.f),
                                fmaxf(acc[mi][2], 0.f), fmaxf(acc[mi][3], 0.f));
        float4 h1 = make_float4(fmaxf(acc[mi][4], 0.f), fmaxf(acc[mi][5], 0.f),
                                fmaxf(acc[mi][6], 0.f), fmaxf(acc[mi][7], 0.f));
        *(float4*)&xs[(tm * 2 + mi) * HSTR + tn * 8]     = h0;
        *(float4*)&xs[(tm * 2 + mi) * HSTR + tn * 8 + 4] = h1;
    }
    __syncthreads();

    // ---- GEMM2: msg = hidden @ W2 + b2, K=256 ----
    float acc2[2][8];
    #pragma unroll
    for (int mi = 0; mi < 2; ++mi)
        #pragma unroll
        for (int ni = 0; ni < 8; ++ni)
            acc2[mi][ni] = b2[tn * 8 + ni];

    for (int k0 = 0; k0 < HID; k0 += 4) {
        float4 a4[2];
        #pragma unroll
        for (int mi = 0; mi < 2; ++mi)
            a4[mi] = *(const float4*)&xs[(tm * 2 + mi) * HSTR + k0];
        #pragma unroll
        for (int kk = 0; kk < 4; ++kk) {
            float4 w0 = *(const float4*)&W2[(size_t)(k0 + kk) * HID + tn * 8];
            float4 w1 = *(const float4*)&W2[(size_t)(k0 + kk) * HID + tn * 8 + 4];
            #pragma unroll
            for (int mi = 0; mi < 2; ++mi) {
                float a = F4C(a4[mi], kk);
                acc2[mi][0] = fmaf(a, w0.x, acc2[mi][0]);
                acc2[mi][1] = fmaf(a, w0.y, acc2[mi][1]);
                acc2[mi][2] = fmaf(a, w0.z, acc2[mi][2]);
                acc2[mi][3] = fmaf(a, w0.w, acc2[mi][3]);
                acc2[mi][4] = fmaf(a, w1.x, acc2[mi][4]);
                acc2[mi][5] = fmaf(a, w1.y, acc2[mi][5]);
                acc2[mi][6] = fmaf(a, w1.z, acc2[mi][6]);
                acc2[mi][7] = fmaf(a, w1.w, acc2[mi][7]);
            }
        }
    }

    // ---- scatter-add into agg[b, dst, :] ----
    #pragma unroll
    for (int mi = 0; mi < 2; ++mi) {
        int d = s_dst[tm * 2 + mi];
        float* base = agg + ((size_t)b * NC + d) * HID + tn * 8;
        #pragma unroll
        for (int ni = 0; ni < 8; ++ni)
            atomicAdd(base + ni, acc2[mi][ni]);
    }
}

__global__ __launch_bounds__(256)
void node_kernel(const float* __restrict__ cell_x,
                 const float* __restrict__ agg,
                 const float* __restrict__ counts,
                 const float* __restrict__ W1, const float* __restrict__ b1,
                 const float* __restrict__ W2, const float* __restrict__ b2,
                 const float* __restrict__ gamma, const float* __restrict__ beta,
                 float* __restrict__ out) {
    __shared__ float xs[MN * XSTR2];      // [cell_x | agg_mean], cell part stays live
    __shared__ float hid[MN * HSTR];      // hidden, later reused for h = cell_x + out
    __shared__ float s_inv[MN];

    const int tid = threadIdx.x;
    const int b   = blockIdx.x >> 8;              // 256 blocks per batch
    const int r0  = (blockIdx.x & 255) * MN;

    if (tid < MN) {
        float c = counts[b * NC + r0 + tid];
        s_inv[tid] = 1.0f / fmaxf(c, 1.0f);
    }
    __syncthreads();

    const int wv = tid >> 6, ln = tid & 63;
    #pragma unroll
    for (int i = 0; i < 4; ++i) {
        int m = wv * 4 + i;
        const float4* crow = (const float4*)(cell_x + ((size_t)b * NC + r0 + m) * HID);
        ((float4*)&xs[m * XSTR2])[ln] = crow[ln];
        const float4* grow = (const float4*)(agg + ((size_t)b * NC + r0 + m) * HID);
        float4 g = grow[ln];
        float inv = s_inv[m];
        g.x *= inv; g.y *= inv; g.z *= inv; g.w *= inv;
        ((float4*)&xs[m * XSTR2 + HID])[ln] = g;
    }
    __syncthreads();

    const int tn = tid & 31, tm = tid >> 5;   // 32 col-groups x 8 row-groups, 2 rows each
    // ---- GEMM1: hidden = relu(U @ W1 + b1), K=512 ----
    float acc[2][8];
    #pragma unroll
    for (int mi = 0; mi < 2; ++mi)
        #pragma unroll
        for (int ni = 0; ni < 8; ++ni)
            acc[mi][ni] = b1[tn * 8 + ni];

    for (int k0 = 0; k0 < 2 * HID; k0 += 4) {
        float4 a4[2];
        #pragma unroll
        for (int mi = 0; mi < 2; ++mi)
            a4[mi] = *(const float4*)&xs[(tm * 2 + mi) * XSTR2 + k0];
        #pragma unroll
        for (int kk = 0; kk < 4; ++kk) {
            float4 w0 = *(const float4*)&W1[(size_t)(k0 + kk) * HID + tn * 8];
            float4 w1 = *(const float4*)&W1[(size_t)(k0 + kk) * HID + tn * 8 + 4];
            #pragma unroll
            for (int mi = 0; mi < 2; ++mi) {
                float a = F4C(a4[mi], kk);
                acc[mi][0] = fmaf(a, w0.x, acc[mi][0]);
                acc[mi][1] = fmaf(a, w0.y, acc[mi][1]);
                acc[mi][2] = fmaf(a, w0.z, acc[mi][2]);
                acc[mi][3] = fmaf(a, w0.w, acc[mi][3]);
                acc[mi][4] = fmaf(a, w1.x, acc[mi][4]);
                acc[mi][5] = fmaf(a, w1.y, acc[mi][5]);
                acc[mi][6] = fmaf(a, w1.z, acc[mi][6]);
                acc[mi][7] = fmaf(a, w1.w, acc[mi][7]);
            }
        }
    }
    #pragma unroll
    for (int mi = 0; mi < 2; ++mi) {
        float4 h0 = make_float4(fmaxf(acc[mi][0], 0.f), fmaxf(acc[mi][1], 0.f),
                                fmaxf(acc[mi][2], 0.f), fmaxf(acc[mi][3], 0.f));
        float4 h1 = make_float4(fmaxf(acc[mi][4], 0.f), fmaxf(acc[mi][5], 0.f),
                                fmaxf(acc[mi][6], 0.f), fmaxf(acc[mi][7], 0.f));
        *(float4*)&hid[(tm * 2 + mi) * HSTR + tn * 8]     = h0;
        *(float4*)&hid[(tm * 2 + mi) * HSTR + tn * 8 + 4] = h1;
    }
    __syncthreads();

    // ---- GEMM2: o = hidden @ W2 + b2, K=256 ----
    float acc2[2][8];
    #pragma unroll
    for (int mi = 0; mi < 2; ++mi)
        #pragma unroll
        for (int ni = 0; ni < 8; ++ni)
            acc2[mi][ni] = b2[tn * 8 + ni];

    for (int k0 = 0; k0 < HID; k0 += 4) {
        float4 a4[2];
        #pragma unroll
        for (int mi = 0; mi < 2; ++mi)
            a4[mi] = *(const float4*)&hid[(tm * 2 + mi) * HSTR + k0];
        #pragma unroll
        for (int kk = 0; kk < 4; ++kk) {
            float4 w0 = *(const float4*)&W2[(size_t)(k0 + kk) * HID + tn * 8];
            float4 w1 = *(const float4*)&W2[(size_t)(k0 + kk) * HID + tn * 8 + 4];
            #pragma unroll
            for (int mi = 0; mi < 2; ++mi) {
                float a = F4C(a4[mi], kk);
                acc2[mi][0] = fmaf(a, w0.x, acc2[mi][0]);
                acc2[mi][1] = fmaf(a, w0.y, acc2[mi][1]);
                acc2[mi][2] = fmaf(a, w0.z, acc2[mi][2]);
                acc2[mi][3] = fmaf(a, w0.w, acc2[mi][3]);
                acc2[mi][4] = fmaf(a, w1.x, acc2[mi][4]);
                acc2[mi][5] = fmaf(a, w1.y, acc2[mi][5]);
                acc2[mi][6] = fmaf(a, w1.z, acc2[mi][6]);
                acc2[mi][7] = fmaf(a, w1.w, acc2[mi][7]);
            }
        }
    }
    __syncthreads();   // all hidden reads done; reuse hid for h = cell_x + o

    #pragma unroll
    for (int mi = 0; mi < 2; ++mi) {
        int m = tm * 2 + mi;
        #pragma unroll
        for (int ni = 0; ni < 8; ++ni) {
            int c = tn * 8 + ni;
            hid[m * HSTR + c] = acc2[mi][ni] + xs[m * XSTR2 + c];
        }
    }
    __syncthreads();

    // ---- LayerNorm per row: wave wv handles rows wv*4 .. wv*4+3 ----
    for (int i = 0; i < 4; ++i) {
        int r = wv * 4 + i;
        float v[4];
        float s = 0.f, q = 0.f;
        #pragma unroll
        for (int j = 0; j < 4; ++j) {
            v[j] = hid[r * HSTR + ln + 64 * j];
            s += v[j];
            q = fmaf(v[j], v[j], q);
        }
        #pragma unroll
        for (int off = 32; off > 0; off >>= 1) {
            s += __shfl_xor(s, off, 64);
            q += __shfl_xor(q, off, 64);
        }
        float mu = s * (1.0f / HID);
        float var = q * (1.0f / HID) - mu * mu;
        float rs = rsqrtf(var + EPSV);
        float* orow = out + ((size_t)b * NC + r0 + r) * HID;
        #pragma unroll
        for (int j = 0; j < 4; ++j) {
            int c = ln + 64 * j;
            orow[c] = (v[j] - mu) * rs * gamma[c] + beta[c];
        }
    }
}

extern "C" void kernel_launch(void* const* d_in, const int* in_sizes, int n_in,
                              void* d_out, int out_size, void* d_ws, size_t ws_size,
                              hipStream_t stream) {
    const float* cell_x = (const float*)d_in[0];
    const int*   eidx   = (const int*)d_in[1];
    const float* eattr  = (const float*)d_in[2];
    const float* mW1    = (const float*)d_in[3];
    const float* mb1    = (const float*)d_in[4];
    const float* mW2    = (const float*)d_in[5];
    const float* mb2    = (const float*)d_in[6];
    const float* uW1    = (const float*)d_in[7];
    const float* ub1    = (const float*)d_in[8];
    const float* uW2    = (const float*)d_in[9];
    const float* ub2    = (const float*)d_in[10];
    const float* gamma  = (const float*)d_in[11];
    const float* beta   = (const float*)d_in[12];
    float* out = (float*)d_out;

    float* agg    = (float*)d_ws;                        // [B, NC, HID]
    float* counts = agg + (size_t)BSZ * NC * HID;        // [B, NC]

    int n4 = (BSZ * NC * HID + BSZ * NC) / 4;
    zero_kernel<<<512, 256, 0, stream>>>((float4*)d_ws, n4);
    count_kernel<<<(BSZ * NE) / 256, 256, 0, stream>>>(eidx, counts);
    edge_kernel<<<BSZ * NE / ME, 256, 0, stream>>>(cell_x, eidx, eattr,
                                                   mW1, mb1, mW2, mb2, agg);
    node_kernel<<<BSZ * NC / MN, 256, 0, stream>>>(cell_x, agg, counts,
                                                   uW1, ub1, uW2, ub2,
                                                   gamma, beta, out);
}

// Round 3
// 669.492 us; speedup vs baseline: 4.3465x; 4.3465x over previous
//
#include <hip/hip_runtime.h>

#define HID 256
#define EF  64
#define KIN 320      // HID + EF
#define NC  4096
#define NE  65536
#define BSZ 4
#define EPSV 1e-5f

typedef unsigned short ushort_t;
typedef __attribute__((ext_vector_type(8))) short s16x8;
typedef __attribute__((ext_vector_type(4))) float f32x4;

// edge kernel (MFMA): 32 edges/block, 4 waves, wave = 2 m-tiles x 4 n-tiles of 16x16
#define ME    32
#define XPAD  328    // bf16 elems/row for X tile: 656B = 164 dw, 164%32=4 -> 2-way max
#define HPAD  264    // bf16 elems/row for H tile: 528B = 132 dw, 132%32=4 -> 2-way max
// node kernel tiling (fp32, unchanged)
#define MN    16
#define XSTR2 516
#define HSTR  260

#define F4C(v, kk) ((kk) == 0 ? (v).x : (kk) == 1 ? (v).y : (kk) == 2 ? (v).z : (v).w)

__device__ __forceinline__ void split_bf16(float v, ushort_t& h, ushort_t& l) {
    unsigned u = __float_as_uint(v);
    h = (ushort_t)(u >> 16);
    float hf = __uint_as_float(u & 0xffff0000u);
    l = (ushort_t)(__float_as_uint(v - hf) >> 16);
}

__global__ void zero_kernel(float4* __restrict__ p, int n4) {
    int i = blockIdx.x * blockDim.x + threadIdx.x;
    int stride = gridDim.x * blockDim.x;
    float4 z = make_float4(0.f, 0.f, 0.f, 0.f);
    for (; i < n4; i += stride) p[i] = z;
}

__global__ __launch_bounds__(256)
void count_kernel(const int* __restrict__ eidx, float* __restrict__ counts) {
    int g = blockIdx.x * 256 + threadIdx.x;
    int d = eidx[(size_t)g * 2 + 1];
    d = min(max(d, 0), NC - 1);
    int b = g >> 16;
    atomicAdd(&counts[b * NC + d], 1.0f);
}

// Pack W (K x 256 row-major) into MFMA B-fragment order, hi/lo bf16.
// idx = (t*16 + n)*64 + lane; element j: W[t*32 + (lane>>4)*8 + j][n*16 + (lane&15)]
__global__ __launch_bounds__(256)
void pack_w(const float* __restrict__ W, int K,
            ushort_t* __restrict__ hi, ushort_t* __restrict__ lo) {
    int idx = blockIdx.x * 256 + threadIdx.x;
    int total = (K / 32) * 16 * 64;
    if (idx >= total) return;
    int l = idx & 63;
    int tn = idx >> 6;
    int n = tn & 15, t = tn >> 4;
    int krow = t * 32 + (l >> 4) * 8;
    int col = n * 16 + (l & 15);
    #pragma unroll
    for (int j = 0; j < 8; ++j) {
        float v = W[(size_t)(krow + j) * 256 + col];
        ushort_t h, lw;
        split_bf16(v, h, lw);
        hi[(size_t)idx * 8 + j] = h;
        lo[(size_t)idx * 8 + j] = lw;
    }
}

__global__ __launch_bounds__(256)
void edge_kernel(const float* __restrict__ cell_x,
                 const int*   __restrict__ eidx,
                 const float* __restrict__ eattr,
                 const ushort_t* __restrict__ w1hi, const ushort_t* __restrict__ w1lo,
                 const float* __restrict__ b1,
                 const ushort_t* __restrict__ w2hi, const ushort_t* __restrict__ w2lo,
                 const float* __restrict__ b2,
                 float* __restrict__ agg) {
    __shared__ ushort_t Xhi[ME * XPAD];   // 21.0 KB; reused as Hhi (HPAD rows fit)
    __shared__ ushort_t Xlo[ME * XPAD];   // 21.0 KB; reused as Hlo
    __shared__ int s_src[ME], s_dst[ME];

    const int tid = threadIdx.x;
    const int b   = blockIdx.x >> 11;            // 2048 blocks per batch
    const int e0  = (blockIdx.x & 2047) * ME;

    if (tid < ME) {
        int2 v = ((const int2*)eidx)[(size_t)b * NE + e0 + tid];
        s_src[tid] = min(max(v.x, 0), NC - 1);
        s_dst[tid] = min(max(v.y, 0), NC - 1);
    }
    __syncthreads();

    // ---- stage X = [src_x | edge_attr] as hi/lo bf16 into LDS ----
    {
        const int row = tid >> 3, c8 = tid & 7;
        const float4* crow = (const float4*)(cell_x + ((size_t)b * NC + s_src[row]) * HID);
        const float4* arow = (const float4*)(eattr + ((size_t)b * NE + e0 + row) * EF);
        #pragma unroll
        for (int i = 0; i < 10; ++i) {
            int c = c8 + i * 8;                       // float4 index, 0..79
            float4 v = (c < 64) ? crow[c] : arow[c - 64];
            ushort_t h0,l0,h1,l1,h2,l2,h3,l3;
            split_bf16(v.x, h0, l0); split_bf16(v.y, h1, l1);
            split_bf16(v.z, h2, l2); split_bf16(v.w, h3, l3);
            int off = row * XPAD + c * 4;
            *(ushort4*)&Xhi[off] = make_ushort4(h0, h1, h2, h3);
            *(ushort4*)&Xlo[off] = make_ushort4(l0, l1, l2, l3);
        }
    }
    __syncthreads();

    const int wv = tid >> 6, ln = tid & 63;
    const int lrow = ln & 15, quad = ln >> 4;

    // ---- GEMM1: hidden = relu(X @ W1 + b1), K=320, 10 k-steps ----
    f32x4 acc[2][4];
    #pragma unroll
    for (int n = 0; n < 4; ++n) {
        float bias = b1[(wv * 4 + n) * 16 + lrow];
        #pragma unroll
        for (int m = 0; m < 2; ++m)
            acc[m][n] = (f32x4){bias, bias, bias, bias};
    }

    #pragma unroll 2
    for (int t = 0; t < 10; ++t) {
        s16x8 ahi[2], alo[2];
        #pragma unroll
        for (int m = 0; m < 2; ++m) {
            int off = (m * 16 + lrow) * XPAD + t * 32 + quad * 8;
            ahi[m] = *(const s16x8*)&Xhi[off];
            alo[m] = *(const s16x8*)&Xlo[off];
        }
        #pragma unroll
        for (int n = 0; n < 4; ++n) {
            size_t boff = ((size_t)(t * 16 + wv * 4 + n) * 64 + ln) * 8;
            s16x8 bhi = *(const s16x8*)(w1hi + boff);
            s16x8 blo = *(const s16x8*)(w1lo + boff);
            #pragma unroll
            for (int m = 0; m < 2; ++m) {
                acc[m][n] = __builtin_amdgcn_mfma_f32_16x16x32_bf16(ahi[m], bhi, acc[m][n], 0, 0, 0);
                acc[m][n] = __builtin_amdgcn_mfma_f32_16x16x32_bf16(ahi[m], blo, acc[m][n], 0, 0, 0);
                acc[m][n] = __builtin_amdgcn_mfma_f32_16x16x32_bf16(alo[m], bhi, acc[m][n], 0, 0, 0);
            }
        }
    }
    __syncthreads();   // all X reads done; reuse LDS for H

    // ---- relu + split + store hidden (A-frag layout rows=edges, HPAD) ----
    ushort_t* Hhi = Xhi;
    ushort_t* Hlo = Xlo;
    #pragma unroll
    for (int m = 0; m < 2; ++m)
        #pragma unroll
        for (int n = 0; n < 4; ++n) {
            int col = (wv * 4 + n) * 16 + lrow;
            #pragma unroll
            for (int r = 0; r < 4; ++r) {
                float v = fmaxf(acc[m][n][r], 0.f);
                int row = m * 16 + quad * 4 + r;
                ushort_t h, l;
                split_bf16(v, h, l);
                Hhi[row * HPAD + col] = h;
                Hlo[row * HPAD + col] = l;
            }
        }
    __syncthreads();

    // ---- GEMM2: msg = hidden @ W2 + b2, K=256, 8 k-steps ----
    f32x4 acc2[2][4];
    #pragma unroll
    for (int n = 0; n < 4; ++n) {
        float bias = b2[(wv * 4 + n) * 16 + lrow];
        #pragma unroll
        for (int m = 0; m < 2; ++m)
            acc2[m][n] = (f32x4){bias, bias, bias, bias};
    }

    #pragma unroll 2
    for (int t = 0; t < 8; ++t) {
        s16x8 ahi[2], alo[2];
        #pragma unroll
        for (int m = 0; m < 2; ++m) {
            int off = (m * 16 + lrow) * HPAD + t * 32 + quad * 8;
            ahi[m] = *(const s16x8*)&Hhi[off];
            alo[m] = *(const s16x8*)&Hlo[off];
        }
        #pragma unroll
        for (int n = 0; n < 4; ++n) {
            size_t boff = ((size_t)(t * 16 + wv * 4 + n) * 64 + ln) * 8;
            s16x8 bhi = *(const s16x8*)(w2hi + boff);
            s16x8 blo = *(const s16x8*)(w2lo + boff);
            #pragma unroll
            for (int m = 0; m < 2; ++m) {
                acc2[m][n] = __builtin_amdgcn_mfma_f32_16x16x32_bf16(ahi[m], bhi, acc2[m][n], 0, 0, 0);
                acc2[m][n] = __builtin_amdgcn_mfma_f32_16x16x32_bf16(ahi[m], blo, acc2[m][n], 0, 0, 0);
                acc2[m][n] = __builtin_amdgcn_mfma_f32_16x16x32_bf16(alo[m], bhi, acc2[m][n], 0, 0, 0);
            }
        }
    }

    // ---- scatter-add into agg[b, dst, :] ----
    #pragma unroll
    for (int m = 0; m < 2; ++m)
        #pragma unroll
        for (int n = 0; n < 4; ++n) {
            int col = (wv * 4 + n) * 16 + lrow;
            #pragma unroll
            for (int r = 0; r < 4; ++r) {
                int d = s_dst[m * 16 + quad * 4 + r];
                atomicAdd(agg + ((size_t)b * NC + d) * HID + col, acc2[m][n][r]);
            }
        }
}

__global__ __launch_bounds__(256)
void node_kernel(const float* __restrict__ cell_x,
                 const float* __restrict__ agg,
                 const float* __restrict__ counts,
                 const float* __restrict__ W1, const float* __restrict__ b1,
                 const float* __restrict__ W2, const float* __restrict__ b2,
                 const float* __restrict__ gamma, const float* __restrict__ beta,
                 float* __restrict__ out) {
    __shared__ float xs[MN * XSTR2];
    __shared__ float hid[MN * HSTR];
    __shared__ float s_inv[MN];

    const int tid = threadIdx.x;
    const int b   = blockIdx.x >> 8;
    const int r0  = (blockIdx.x & 255) * MN;

    if (tid < MN) {
        float c = counts[b * NC + r0 + tid];
        s_inv[tid] = 1.0f / fmaxf(c, 1.0f);
    }
    __syncthreads();

    const int wv = tid >> 6, ln = tid & 63;
    #pragma unroll
    for (int i = 0; i < 4; ++i) {
        int m = wv * 4 + i;
        const float4* crow = (const float4*)(cell_x + ((size_t)b * NC + r0 + m) * HID);
        ((float4*)&xs[m * XSTR2])[ln] = crow[ln];
        const float4* grow = (const float4*)(agg + ((size_t)b * NC + r0 + m) * HID);
        float4 g = grow[ln];
        float inv = s_inv[m];
        g.x *= inv; g.y *= inv; g.z *= inv; g.w *= inv;
        ((float4*)&xs[m * XSTR2 + HID])[ln] = g;
    }
    __syncthreads();

    const int tn = tid & 31, tm = tid >> 5;
    float acc[2][8];
    #pragma unroll
    for (int mi = 0; mi < 2; ++mi)
        #pragma unroll
        for (int ni = 0; ni < 8; ++ni)
            acc[mi][ni] = b1[tn * 8 + ni];

    for (int k0 = 0; k0 < 2 * HID; k0 += 4) {
        float4 a4[2];
        #pragma unroll
        for (int mi = 0; mi < 2; ++mi)
            a4[mi] = *(const float4*)&xs[(tm * 2 + mi) * XSTR2 + k0];
        #pragma unroll
        for (int kk = 0; kk < 4; ++kk) {
            float4 w0 = *(const float4*)&W1[(size_t)(k0 + kk) * HID + tn * 8];
            float4 w1 = *(const float4*)&W1[(size_t)(k0 + kk) * HID + tn * 8 + 4];
            #pragma unroll
            for (int mi = 0; mi < 2; ++mi) {
                float a = F4C(a4[mi], kk);
                acc[mi][0] = fmaf(a, w0.x, acc[mi][0]);
                acc[mi][1] = fmaf(a, w0.y, acc[mi][1]);
                acc[mi][2] = fmaf(a, w0.z, acc[mi][2]);
                acc[mi][3] = fmaf(a, w0.w, acc[mi][3]);
                acc[mi][4] = fmaf(a, w1.x, acc[mi][4]);
                acc[mi][5] = fmaf(a, w1.y, acc[mi][5]);
                acc[mi][6] = fmaf(a, w1.z, acc[mi][6]);
                acc[mi][7] = fmaf(a, w1.w, acc[mi][7]);
            }
        }
    }
    #pragma unroll
    for (int mi = 0; mi < 2; ++mi) {
        float4 h0 = make_float4(fmaxf(acc[mi][0], 0.f), fmaxf(acc[mi][1], 0.f),
                                fmaxf(acc[mi][2], 0.f), fmaxf(acc[mi][3], 0.f));
        float4 h1 = make_float4(fmaxf(acc[mi][4], 0.f), fmaxf(acc[mi][5], 0.f),
                                fmaxf(acc[mi][6], 0.f), fmaxf(acc[mi][7], 0.f));
        *(float4*)&hid[(tm * 2 + mi) * HSTR + tn * 8]     = h0;
        *(float4*)&hid[(tm * 2 + mi) * HSTR + tn * 8 + 4] = h1;
    }
    __syncthreads();

    float acc2[2][8];
    #pragma unroll
    for (int mi = 0; mi < 2; ++mi)
        #pragma unroll
        for (int ni = 0; ni < 8; ++ni)
            acc2[mi][ni] = b2[tn * 8 + ni];

    for (int k0 = 0; k0 < HID; k0 += 4) {
        float4 a4[2];
        #pragma unroll
        for (int mi = 0; mi < 2; ++mi)
            a4[mi] = *(const float4*)&hid[(tm * 2 + mi) * HSTR + k0];
        #pragma unroll
        for (int kk = 0; kk < 4; ++kk) {
            float4 w0 = *(const float4*)&W2[(size_t)(k0 + kk) * HID + tn * 8];
            float4 w1 = *(const float4*)&W2[(size_t)(k0 + kk) * HID + tn * 8 + 4];
            #pragma unroll
            for (int mi = 0; mi < 2; ++mi) {
                float a = F4C(a4[mi], kk);
                acc2[mi][0] = fmaf(a, w0.x, acc2[mi][0]);
                acc2[mi][1] = fmaf(a, w0.y, acc2[mi][1]);
                acc2[mi][2] = fmaf(a, w0.z, acc2[mi][2]);
                acc2[mi][3] = fmaf(a, w0.w, acc2[mi][3]);
                acc2[mi][4] = fmaf(a, w1.x, acc2[mi][4]);
                acc2[mi][5] = fmaf(a, w1.y, acc2[mi][5]);
                acc2[mi][6] = fmaf(a, w1.z, acc2[mi][6]);
                acc2[mi][7] = fmaf(a, w1.w, acc2[mi][7]);
            }
        }
    }
    __syncthreads();

    #pragma unroll
    for (int mi = 0; mi < 2; ++mi) {
        int m = tm * 2 + mi;
        #pragma unroll
        for (int ni = 0; ni < 8; ++ni) {
            int c = tn * 8 + ni;
            hid[m * HSTR + c] = acc2[mi][ni] + xs[m * XSTR2 + c];
        }
    }
    __syncthreads();

    for (int i = 0; i < 4; ++i) {
        int r = wv * 4 + i;
        float v[4];
        float s = 0.f, q = 0.f;
        #pragma unroll
        for (int j = 0; j < 4; ++j) {
            v[j] = hid[r * HSTR + ln + 64 * j];
            s += v[j];
            q = fmaf(v[j], v[j], q);
        }
        #pragma unroll
        for (int off = 32; off > 0; off >>= 1) {
            s += __shfl_xor(s, off, 64);
            q += __shfl_xor(q, off, 64);
        }
        float mu = s * (1.0f / HID);
        float var = q * (1.0f / HID) - mu * mu;
        float rs = rsqrtf(var + EPSV);
        float* orow = out + ((size_t)b * NC + r0 + r) * HID;
        #pragma unroll
        for (int j = 0; j < 4; ++j) {
            int c = ln + 64 * j;
            orow[c] = (v[j] - mu) * rs * gamma[c] + beta[c];
        }
    }
}

extern "C" void kernel_launch(void* const* d_in, const int* in_sizes, int n_in,
                              void* d_out, int out_size, void* d_ws, size_t ws_size,
                              hipStream_t stream) {
    const float* cell_x = (const float*)d_in[0];
    const int*   eidx   = (const int*)d_in[1];
    const float* eattr  = (const float*)d_in[2];
    const float* mW1    = (const float*)d_in[3];
    const float* mb1    = (const float*)d_in[4];
    const float* mW2    = (const float*)d_in[5];
    const float* mb2    = (const float*)d_in[6];
    const float* uW1    = (const float*)d_in[7];
    const float* ub1    = (const float*)d_in[8];
    const float* uW2    = (const float*)d_in[9];
    const float* ub2    = (const float*)d_in[10];
    const float* gamma  = (const float*)d_in[11];
    const float* beta   = (const float*)d_in[12];
    float* out = (float*)d_out;

    float* agg    = (float*)d_ws;                        // [B, NC, HID] fp32
    float* counts = agg + (size_t)BSZ * NC * HID;        // [B, NC]
    ushort_t* w1hi = (ushort_t*)(counts + BSZ * NC);     // packed W1: 320*256 bf16
    ushort_t* w1lo = w1hi + KIN * HID;
    ushort_t* w2hi = w1lo + KIN * HID;                   // packed W2: 256*256 bf16
    ushort_t* w2lo = w2hi + HID * HID;

    int n4 = (BSZ * NC * HID + BSZ * NC) / 4;
    zero_kernel<<<512, 256, 0, stream>>>((float4*)d_ws, n4);
    pack_w<<<(KIN / 32 * 16 * 64 + 255) / 256, 256, 0, stream>>>(mW1, KIN, w1hi, w1lo);
    pack_w<<<(HID / 32 * 16 * 64 + 255) / 256, 256, 0, stream>>>(mW2, HID, w2hi, w2lo);
    count_kernel<<<(BSZ * NE) / 256, 256, 0, stream>>>(eidx, counts);
    edge_kernel<<<BSZ * NE / ME, 256, 0, stream>>>(cell_x, eidx, eattr,
                                                   w1hi, w1lo, mb1, w2hi, w2lo, mb2, agg);
    node_kernel<<<BSZ * NC / MN, 256, 0, stream>>>(cell_x, agg, counts,
                                                   uW1, ub1, uW2, ub2,
                                                   gamma, beta, out);
}

// Round 4
// 461.057 us; speedup vs baseline: 6.3115x; 1.4521x over previous
//
#include <hip/hip_runtime.h>

#define HID 256
#define EF  64
#define KIN 320      // HID + EF
#define NC  4096
#define NE  65536
#define BSZ 4
#define EPSV 1e-5f

typedef unsigned short ushort_t;
typedef __attribute__((ext_vector_type(8))) short s16x8;
typedef __attribute__((ext_vector_type(16))) float f32x16;

// LDS strides (in ushort elements); byte strides are 16B-aligned
#define XPAD  328    // edge X tile: 656 B/row
#define HPAD  264    // hidden tile: 528 B/row
#define UPAD  520    // node U tile: 1040 B/row
#define HSF   260    // node h (fp32) stride

__device__ __forceinline__ void split_bf16(float v, ushort_t& h, ushort_t& l) {
    unsigned u = __float_as_uint(v);
    h = (ushort_t)(u >> 16);
    float hf = __uint_as_float(u & 0xffff0000u);
    l = (ushort_t)(__float_as_uint(v - hf) >> 16);
}

__global__ void zero_kernel(float4* __restrict__ p, int n4) {
    int i = blockIdx.x * blockDim.x + threadIdx.x;
    int stride = gridDim.x * blockDim.x;
    float4 z = make_float4(0.f, 0.f, 0.f, 0.f);
    for (; i < n4; i += stride) p[i] = z;
}

__global__ __launch_bounds__(256)
void count_kernel(const int* __restrict__ eidx, float* __restrict__ counts) {
    int g = blockIdx.x * 256 + threadIdx.x;
    int d = eidx[(size_t)g * 2 + 1];
    d = min(max(d, 0), NC - 1);
    int b = g >> 16;
    atomicAdd(&counts[b * NC + d], 1.0f);
}

// Pack W [K][256] row-major into 32x32x16 MFMA B-fragment order, hi/lo bf16.
// frag idx = (t*8 + nt)*64 + lane; elem j: W[t*16 + (lane>>5)*8 + j][nt*32 + (lane&31)]
__global__ __launch_bounds__(256)
void pack_w(const float* __restrict__ W, int K,
            ushort_t* __restrict__ hi, ushort_t* __restrict__ lo) {
    int idx = blockIdx.x * 256 + threadIdx.x;
    int total = (K / 16) * 8 * 64;
    if (idx >= total) return;
    int l = idx & 63;
    int tn = idx >> 6;
    int nt = tn & 7, t = tn >> 3;
    int k0 = t * 16 + (l >> 5) * 8;
    int col = nt * 32 + (l & 31);
    #pragma unroll
    for (int j = 0; j < 8; ++j) {
        float v = W[(size_t)(k0 + j) * 256 + col];
        ushort_t h, lw;
        split_bf16(v, h, lw);
        hi[(size_t)idx * 8 + j] = h;
        lo[(size_t)idx * 8 + j] = lw;
    }
}

// 32 edges/block, 512 threads = 8 waves; wave wv owns n-tile wv (cols wv*32..+31)
__global__ __launch_bounds__(512, 6)
void edge_kernel(const float* __restrict__ cell_x,
                 const int*   __restrict__ eidx,
                 const float* __restrict__ eattr,
                 const ushort_t* __restrict__ w1hi, const ushort_t* __restrict__ w1lo,
                 const float* __restrict__ b1,
                 const ushort_t* __restrict__ w2hi, const ushort_t* __restrict__ w2lo,
                 const float* __restrict__ b2,
                 float* __restrict__ agg) {
    __shared__ ushort_t pool[2 * 32 * XPAD];   // 41,984 B; X tile, reused as H tile
    __shared__ int s_src[32], s_dst[32];
    ushort_t* Xhi = pool;
    ushort_t* Xlo = pool + 32 * XPAD;
    ushort_t* Hhi = Xhi;                        // 32*HPAD fits within 32*XPAD
    ushort_t* Hlo = Xlo;

    const int tid = threadIdx.x;
    const int b   = blockIdx.x >> 11;            // 2048 blocks per batch
    const int e0  = (blockIdx.x & 2047) * 32;

    if (tid < 32) {
        int2 v = ((const int2*)eidx)[(size_t)b * NE + e0 + tid];
        s_src[tid] = min(max(v.x, 0), NC - 1);
        s_dst[tid] = min(max(v.y, 0), NC - 1);
    }
    __syncthreads();

    // ---- stage X = [src_x | edge_attr] as hi/lo bf16 ----
    {
        const int row = tid >> 4, c8 = tid & 15;
        const float4* crow = (const float4*)(cell_x + ((size_t)b * NC + s_src[row]) * HID);
        const float4* arow = (const float4*)(eattr + ((size_t)b * NE + e0 + row) * EF);
        #pragma unroll
        for (int i = 0; i < 5; ++i) {
            int c = c8 + i * 16;                 // float4 index 0..79
            float4 v = (c < 64) ? crow[c] : arow[c - 64];
            ushort_t h0,l0,h1,l1,h2,l2,h3,l3;
            split_bf16(v.x, h0, l0); split_bf16(v.y, h1, l1);
            split_bf16(v.z, h2, l2); split_bf16(v.w, h3, l3);
            int off = row * XPAD + c * 4;
            *(ushort4*)&Xhi[off] = make_ushort4(h0, h1, h2, h3);
            *(ushort4*)&Xlo[off] = make_ushort4(l0, l1, l2, l3);
        }
    }
    __syncthreads();

    const int wv = tid >> 6, ln = tid & 63;
    const int m32 = ln & 31, half = ln >> 5;
    const int col = wv * 32 + m32;               // this lane's output column

    // ---- GEMM1: hidden = relu(X @ W1 + b1), K=320, 20 k-steps ----
    f32x16 acc;
    {
        float bias = b1[col];
        #pragma unroll
        for (int r = 0; r < 16; ++r) acc[r] = bias;
    }
    #pragma unroll 2
    for (int t = 0; t < 20; ++t) {
        int aoff = m32 * XPAD + t * 16 + half * 8;
        s16x8 ahi = *(const s16x8*)&Xhi[aoff];
        s16x8 alo = *(const s16x8*)&Xlo[aoff];
        size_t boff = ((size_t)(t * 8 + wv) * 64 + ln) * 8;
        s16x8 bhi = *(const s16x8*)(w1hi + boff);
        s16x8 blo = *(const s16x8*)(w1lo + boff);
        acc = __builtin_amdgcn_mfma_f32_32x32x16_bf16(ahi, bhi, acc, 0, 0, 0);
        acc = __builtin_amdgcn_mfma_f32_32x32x16_bf16(ahi, blo, acc, 0, 0, 0);
        acc = __builtin_amdgcn_mfma_f32_32x32x16_bf16(alo, bhi, acc, 0, 0, 0);
    }
    __syncthreads();   // all X reads done; reuse LDS for H

    // ---- relu + split + store hidden (rows=edges) ----
    #pragma unroll
    for (int r = 0; r < 16; ++r) {
        float v = fmaxf(acc[r], 0.f);
        int row = (r & 3) + 8 * (r >> 2) + 4 * half;
        ushort_t h, l;
        split_bf16(v, h, l);
        Hhi[row * HPAD + col] = h;
        Hlo[row * HPAD + col] = l;
    }
    __syncthreads();

    // ---- GEMM2: msg = hidden @ W2 + b2, K=256, 16 k-steps ----
    f32x16 acc2;
    {
        float bias = b2[col];
        #pragma unroll
        for (int r = 0; r < 16; ++r) acc2[r] = bias;
    }
    #pragma unroll 2
    for (int t = 0; t < 16; ++t) {
        int aoff = m32 * HPAD + t * 16 + half * 8;
        s16x8 ahi = *(const s16x8*)&Hhi[aoff];
        s16x8 alo = *(const s16x8*)&Hlo[aoff];
        size_t boff = ((size_t)(t * 8 + wv) * 64 + ln) * 8;
        s16x8 bhi = *(const s16x8*)(w2hi + boff);
        s16x8 blo = *(const s16x8*)(w2lo + boff);
        acc2 = __builtin_amdgcn_mfma_f32_32x32x16_bf16(ahi, bhi, acc2, 0, 0, 0);
        acc2 = __builtin_amdgcn_mfma_f32_32x32x16_bf16(ahi, blo, acc2, 0, 0, 0);
        acc2 = __builtin_amdgcn_mfma_f32_32x32x16_bf16(alo, bhi, acc2, 0, 0, 0);
    }

    // ---- scatter-add into agg[b, dst, col] ----
    #pragma unroll
    for (int r = 0; r < 16; ++r) {
        int row = (r & 3) + 8 * (r >> 2) + 4 * half;
        atomicAdd(agg + ((size_t)b * NC + s_dst[row]) * HID + col, acc2[r]);
    }
}

// 32 nodes/block, 512 threads = 8 waves; wave wv owns n-tile wv
__global__ __launch_bounds__(512, 4)
void node_kernel(const float* __restrict__ cell_x,
                 const float* __restrict__ agg,
                 const float* __restrict__ counts,
                 const ushort_t* __restrict__ w1hi, const ushort_t* __restrict__ w1lo,
                 const float* __restrict__ b1,
                 const ushort_t* __restrict__ w2hi, const ushort_t* __restrict__ w2lo,
                 const float* __restrict__ b2,
                 const float* __restrict__ gamma, const float* __restrict__ beta,
                 float* __restrict__ out) {
    __shared__ ushort_t pool[2 * 32 * UPAD];   // 66,560 B
    __shared__ float s_inv[32];
    ushort_t* Uhi = pool;
    ushort_t* Ulo = pool + 32 * UPAD;
    ushort_t* Hhi = Uhi;                        // overlay after GEMM1
    ushort_t* Hlo = Ulo;
    float*    hs  = (float*)pool;               // overlay after GEMM2 (32*HSF*4 B)

    const int tid = threadIdx.x;
    const int b   = blockIdx.x >> 7;             // 128 blocks per batch
    const int r0  = (blockIdx.x & 127) * 32;

    if (tid < 32) {
        float c = counts[b * NC + r0 + tid];
        s_inv[tid] = 1.0f / fmaxf(c, 1.0f);
    }
    __syncthreads();

    // ---- stage U = [cell_x | agg/cnt] hi/lo bf16 ----
    {
        const int row = tid >> 4, c8 = tid & 15;
        const float4* crow = (const float4*)(cell_x + ((size_t)b * NC + r0 + row) * HID);
        const float4* grow = (const float4*)(agg + ((size_t)b * NC + r0 + row) * HID);
        float inv = s_inv[row];
        #pragma unroll
        for (int i = 0; i < 8; ++i) {
            int c = c8 + i * 16;                 // float4 index 0..127
            float4 v;
            if (c < 64) v = crow[c];
            else {
                v = grow[c - 64];
                v.x *= inv; v.y *= inv; v.z *= inv; v.w *= inv;
            }
            ushort_t h0,l0,h1,l1,h2,l2,h3,l3;
            split_bf16(v.x, h0, l0); split_bf16(v.y, h1, l1);
            split_bf16(v.z, h2, l2); split_bf16(v.w, h3, l3);
            int off = row * UPAD + c * 4;
            *(ushort4*)&Uhi[off] = make_ushort4(h0, h1, h2, h3);
            *(ushort4*)&Ulo[off] = make_ushort4(l0, l1, l2, l3);
        }
    }
    __syncthreads();

    const int wv = tid >> 6, ln = tid & 63;
    const int m32 = ln & 31, half = ln >> 5;
    const int col = wv * 32 + m32;

    // ---- GEMM1: hidden = relu(U @ uW1 + ub1), K=512, 32 k-steps ----
    f32x16 acc;
    {
        float bias = b1[col];
        #pragma unroll
        for (int r = 0; r < 16; ++r) acc[r] = bias;
    }
    #pragma unroll 2
    for (int t = 0; t < 32; ++t) {
        int aoff = m32 * UPAD + t * 16 + half * 8;
        s16x8 ahi = *(const s16x8*)&Uhi[aoff];
        s16x8 alo = *(const s16x8*)&Ulo[aoff];
        size_t boff = ((size_t)(t * 8 + wv) * 64 + ln) * 8;
        s16x8 bhi = *(const s16x8*)(w1hi + boff);
        s16x8 blo = *(const s16x8*)(w1lo + boff);
        acc = __builtin_amdgcn_mfma_f32_32x32x16_bf16(ahi, bhi, acc, 0, 0, 0);
        acc = __builtin_amdgcn_mfma_f32_32x32x16_bf16(ahi, blo, acc, 0, 0, 0);
        acc = __builtin_amdgcn_mfma_f32_32x32x16_bf16(alo, bhi, acc, 0, 0, 0);
    }
    __syncthreads();   // U dead; reuse for H

    #pragma unroll
    for (int r = 0; r < 16; ++r) {
        float v = fmaxf(acc[r], 0.f);
        int row = (r & 3) + 8 * (r >> 2) + 4 * half;
        ushort_t h, l;
        split_bf16(v, h, l);
        Hhi[row * HPAD + col] = h;
        Hlo[row * HPAD + col] = l;
    }
    __syncthreads();

    // ---- GEMM2: o = hidden @ uW2 + ub2, K=256, 16 k-steps ----
    f32x16 acc2;
    {
        float bias = b2[col];
        #pragma unroll
        for (int r = 0; r < 16; ++r) acc2[r] = bias;
    }
    #pragma unroll 2
    for (int t = 0; t < 16; ++t) {
        int aoff = m32 * HPAD + t * 16 + half * 8;
        s16x8 ahi = *(const s16x8*)&Hhi[aoff];
        s16x8 alo = *(const s16x8*)&Hlo[aoff];
        size_t boff = ((size_t)(t * 8 + wv) * 64 + ln) * 8;
        s16x8 bhi = *(const s16x8*)(w2hi + boff);
        s16x8 blo = *(const s16x8*)(w2lo + boff);
        acc2 = __builtin_amdgcn_mfma_f32_32x32x16_bf16(ahi, bhi, acc2, 0, 0, 0);
        acc2 = __builtin_amdgcn_mfma_f32_32x32x16_bf16(ahi, blo, acc2, 0, 0, 0);
        acc2 = __builtin_amdgcn_mfma_f32_32x32x16_bf16(alo, bhi, acc2, 0, 0, 0);
    }
    __syncthreads();   // H dead; reuse pool for hs (fp32)

    // ---- residual: h = cell_x + o, into LDS ----
    #pragma unroll
    for (int r = 0; r < 16; ++r) {
        int row = (r & 3) + 8 * (r >> 2) + 4 * half;
        float cx = cell_x[((size_t)b * NC + r0 + row) * HID + col];
        hs[row * HSF + col] = acc2[r] + cx;
    }
    __syncthreads();

    // ---- LayerNorm per row: wave wv handles rows wv*4..+3 ----
    #pragma unroll
    for (int i = 0; i < 4; ++i) {
        int r = wv * 4 + i;
        float v[4];
        float s = 0.f, q = 0.f;
        #pragma unroll
        for (int j = 0; j < 4; ++j) {
            v[j] = hs[r * HSF + ln + 64 * j];
            s += v[j];
            q = fmaf(v[j], v[j], q);
        }
        #pragma unroll
        for (int off = 32; off > 0; off >>= 1) {
            s += __shfl_xor(s, off, 64);
            q += __shfl_xor(q, off, 64);
        }
        float mu = s * (1.0f / HID);
        float var = q * (1.0f / HID) - mu * mu;
        float rs = rsqrtf(var + EPSV);
        float* orow = out + ((size_t)b * NC + r0 + r) * HID;
        #pragma unroll
        for (int j = 0; j < 4; ++j) {
            int c = ln + 64 * j;
            orow[c] = (v[j] - mu) * rs * gamma[c] + beta[c];
        }
    }
}

extern "C" void kernel_launch(void* const* d_in, const int* in_sizes, int n_in,
                              void* d_out, int out_size, void* d_ws, size_t ws_size,
                              hipStream_t stream) {
    const float* cell_x = (const float*)d_in[0];
    const int*   eidx   = (const int*)d_in[1];
    const float* eattr  = (const float*)d_in[2];
    const float* mW1    = (const float*)d_in[3];
    const float* mb1    = (const float*)d_in[4];
    const float* mW2    = (const float*)d_in[5];
    const float* mb2    = (const float*)d_in[6];
    const float* uW1    = (const float*)d_in[7];
    const float* ub1    = (const float*)d_in[8];
    const float* uW2    = (const float*)d_in[9];
    const float* ub2    = (const float*)d_in[10];
    const float* gamma  = (const float*)d_in[11];
    const float* beta   = (const float*)d_in[12];
    float* out = (float*)d_out;

    float* agg    = (float*)d_ws;                        // [B, NC, HID] fp32
    float* counts = agg + (size_t)BSZ * NC * HID;        // [B, NC]
    ushort_t* w1hi = (ushort_t*)(counts + BSZ * NC);     // packed mW1: 320*256
    ushort_t* w1lo = w1hi + KIN * HID;
    ushort_t* w2hi = w1lo + KIN * HID;                   // packed mW2: 256*256
    ushort_t* w2lo = w2hi + HID * HID;
    ushort_t* u1hi = w2lo + HID * HID;                   // packed uW1: 512*256
    ushort_t* u1lo = u1hi + 2 * HID * HID;
    ushort_t* u2hi = u1lo + 2 * HID * HID;               // packed uW2: 256*256
    ushort_t* u2lo = u2hi + HID * HID;

    int n4 = (BSZ * NC * HID + BSZ * NC) / 4;
    zero_kernel<<<512, 256, 0, stream>>>((float4*)d_ws, n4);
    pack_w<<<(KIN / 16 * 8 * 64 + 255) / 256, 256, 0, stream>>>(mW1, KIN, w1hi, w1lo);
    pack_w<<<(HID / 16 * 8 * 64 + 255) / 256, 256, 0, stream>>>(mW2, HID, w2hi, w2lo);
    pack_w<<<(2 * HID / 16 * 8 * 64 + 255) / 256, 256, 0, stream>>>(uW1, 2 * HID, u1hi, u1lo);
    pack_w<<<(HID / 16 * 8 * 64 + 255) / 256, 256, 0, stream>>>(uW2, HID, u2hi, u2lo);
    count_kernel<<<(BSZ * NE) / 256, 256, 0, stream>>>(eidx, counts);
    edge_kernel<<<BSZ * NE / 32, 512, 0, stream>>>(cell_x, eidx, eattr,
                                                   w1hi, w1lo, mb1, w2hi, w2lo, mb2, agg);
    node_kernel<<<BSZ * NC / 32, 512, 0, stream>>>(cell_x, agg, counts,
                                                   u1hi, u1lo, ub1, u2hi, u2lo, ub2,
                                                   gamma, beta, out);
}

// Round 5
// 425.679 us; speedup vs baseline: 6.8361x; 1.0831x over previous
//
#include <hip/hip_runtime.h>

#define HID 256
#define EF  64
#define KIN 320      // HID + EF
#define NC  4096
#define NE  65536
#define BSZ 4
#define EPSV 1e-5f

typedef unsigned short ushort_t;
typedef __attribute__((ext_vector_type(8))) short s16x8;
typedef __attribute__((ext_vector_type(16))) float f32x16;

// LDS strides in ushort elements
#define XPAD 328     // edge X tile row: 656 B
#define HPAD 264     // hidden tile row: 528 B
#define UPAD 520     // node U tile row: 1040 B
#define HSF  260     // node h (fp32) stride

// round-to-nearest-even fp32 -> bf16
__device__ __forceinline__ ushort_t bf16_rne(float f) {
    unsigned u = __float_as_uint(f);
    return (ushort_t)((u + 0x7fffu + ((u >> 16) & 1u)) >> 16);
}
// truncating hi/lo split (pair sums to ~fp32 precision) — for weights (B operand)
__device__ __forceinline__ void split_bf16(float v, ushort_t& h, ushort_t& l) {
    unsigned u = __float_as_uint(v);
    h = (ushort_t)(u >> 16);
    float hf = __uint_as_float(u & 0xffff0000u);
    l = (ushort_t)(__float_as_uint(v - hf) >> 16);
}

__global__ void zero_kernel(float4* __restrict__ p, int n4) {
    int i = blockIdx.x * blockDim.x + threadIdx.x;
    int stride = gridDim.x * blockDim.x;
    float4 z = make_float4(0.f, 0.f, 0.f, 0.f);
    for (; i < n4; i += stride) p[i] = z;
}

__global__ __launch_bounds__(256)
void count_kernel(const int* __restrict__ eidx, float* __restrict__ counts) {
    int g = blockIdx.x * 256 + threadIdx.x;
    int d = eidx[(size_t)g * 2 + 1];
    d = min(max(d, 0), NC - 1);
    int b = g >> 16;
    atomicAdd(&counts[b * NC + d], 1.0f);
}

// Pack W [K][256] row-major into 32x32x16 MFMA B-fragment order, hi/lo bf16.
// frag idx = (t*8 + nt)*64 + lane; elem j: W[t*16 + (lane>>5)*8 + j][nt*32 + (lane&31)]
__global__ __launch_bounds__(256)
void pack_w(const float* __restrict__ W, int K,
            ushort_t* __restrict__ hi, ushort_t* __restrict__ lo) {
    int idx = blockIdx.x * 256 + threadIdx.x;
    int total = (K / 16) * 8 * 64;
    if (idx >= total) return;
    int l = idx & 63;
    int tn = idx >> 6;
    int nt = tn & 7, t = tn >> 3;
    int k0 = t * 16 + (l >> 5) * 8;
    int col = nt * 32 + (l & 31);
    #pragma unroll
    for (int j = 0; j < 8; ++j) {
        float v = W[(size_t)(k0 + j) * 256 + col];
        ushort_t h, lw;
        split_bf16(v, h, lw);
        hi[(size_t)idx * 8 + j] = h;
        lo[(size_t)idx * 8 + j] = lw;
    }
}

// 64 edges/block, 512 threads = 8 waves; wave wv owns n-tile wv, 2 m-tiles
__global__ __launch_bounds__(512, 6)
void edge_kernel(const float* __restrict__ cell_x,
                 const int*   __restrict__ eidx,
                 const float* __restrict__ eattr,
                 const ushort_t* __restrict__ w1hi, const ushort_t* __restrict__ w1lo,
                 const float* __restrict__ b1,
                 const ushort_t* __restrict__ w2hi, const ushort_t* __restrict__ w2lo,
                 const float* __restrict__ b2,
                 float* __restrict__ agg) {
    __shared__ ushort_t Xs[64 * XPAD];   // 41,984 B; reused as H (64*HPAD = 33,792 B)
    __shared__ int s_src[64], s_dst[64];

    const int tid = threadIdx.x;
    const int b   = blockIdx.x >> 10;            // 1024 blocks per batch
    const int e0  = (blockIdx.x & 1023) * 64;

    if (tid < 64) {
        int2 v = ((const int2*)eidx)[(size_t)b * NE + e0 + tid];
        s_src[tid] = min(max(v.x, 0), NC - 1);
        s_dst[tid] = min(max(v.y, 0), NC - 1);
    }
    __syncthreads();

    // ---- stage X = [src_x | edge_attr] as RNE bf16 ----
    {
        const int row = tid >> 3, c8 = tid & 7;
        const float4* crow = (const float4*)(cell_x + ((size_t)b * NC + s_src[row]) * HID);
        const float4* arow = (const float4*)(eattr + ((size_t)b * NE + e0 + row) * EF);
        #pragma unroll
        for (int i = 0; i < 10; ++i) {
            int c = c8 + i * 8;                  // float4 index 0..79
            float4 v = (c < 64) ? crow[c] : arow[c - 64];
            *(ushort4*)&Xs[row * XPAD + c * 4] =
                make_ushort4(bf16_rne(v.x), bf16_rne(v.y), bf16_rne(v.z), bf16_rne(v.w));
        }
    }
    __syncthreads();

    const int wv = tid >> 6, ln = tid & 63;
    const int m32 = ln & 31, half = ln >> 5;
    const int col = wv * 32 + m32;

    // ---- GEMM1: hidden = relu(X @ W1 + b1), K=320, 20 k-steps ----
    f32x16 acc0, acc1;
    {
        float bias = b1[col];
        #pragma unroll
        for (int r = 0; r < 16; ++r) { acc0[r] = bias; acc1[r] = bias; }
    }
    {
        const ushort_t* bph = w1hi + ((size_t)wv * 64 + ln) * 8;
        const ushort_t* bpl = w1lo + ((size_t)wv * 64 + ln) * 8;
        s16x8 bhi = *(const s16x8*)bph;
        s16x8 blo = *(const s16x8*)bpl;
        #pragma unroll 2
        for (int t = 0; t < 20; ++t) {
            int tn1 = (t + 1 < 20) ? t + 1 : 19;
            s16x8 bhin = *(const s16x8*)(bph + (size_t)tn1 * 4096);
            s16x8 blon = *(const s16x8*)(bpl + (size_t)tn1 * 4096);
            int ao = m32 * XPAD + t * 16 + half * 8;
            s16x8 a0 = *(const s16x8*)&Xs[ao];
            s16x8 a1 = *(const s16x8*)&Xs[ao + 32 * XPAD];
            acc0 = __builtin_amdgcn_mfma_f32_32x32x16_bf16(a0, bhi, acc0, 0, 0, 0);
            acc0 = __builtin_amdgcn_mfma_f32_32x32x16_bf16(a0, blo, acc0, 0, 0, 0);
            acc1 = __builtin_amdgcn_mfma_f32_32x32x16_bf16(a1, bhi, acc1, 0, 0, 0);
            acc1 = __builtin_amdgcn_mfma_f32_32x32x16_bf16(a1, blo, acc1, 0, 0, 0);
            bhi = bhin; blo = blon;
        }
    }
    __syncthreads();   // all X reads done; reuse LDS for H

    // ---- relu + RNE bf16 + store hidden (rows = edges) ----
    #pragma unroll
    for (int r = 0; r < 16; ++r) {
        int row = (r & 3) + 8 * (r >> 2) + 4 * half;
        Xs[row * HPAD + col]        = bf16_rne(fmaxf(acc0[r], 0.f));
        Xs[(row + 32) * HPAD + col] = bf16_rne(fmaxf(acc1[r], 0.f));
    }
    __syncthreads();

    // ---- GEMM2: msg = hidden @ W2 + b2, K=256, 16 k-steps ----
    f32x16 c0, c1;
    {
        float bias = b2[col];
        #pragma unroll
        for (int r = 0; r < 16; ++r) { c0[r] = bias; c1[r] = bias; }
    }
    {
        const ushort_t* bph = w2hi + ((size_t)wv * 64 + ln) * 8;
        const ushort_t* bpl = w2lo + ((size_t)wv * 64 + ln) * 8;
        s16x8 bhi = *(const s16x8*)bph;
        s16x8 blo = *(const s16x8*)bpl;
        #pragma unroll 2
        for (int t = 0; t < 16; ++t) {
            int tn1 = (t + 1 < 16) ? t + 1 : 15;
            s16x8 bhin = *(const s16x8*)(bph + (size_t)tn1 * 4096);
            s16x8 blon = *(const s16x8*)(bpl + (size_t)tn1 * 4096);
            int ao = m32 * HPAD + t * 16 + half * 8;
            s16x8 a0 = *(const s16x8*)&Xs[ao];
            s16x8 a1 = *(const s16x8*)&Xs[ao + 32 * HPAD];
            c0 = __builtin_amdgcn_mfma_f32_32x32x16_bf16(a0, bhi, c0, 0, 0, 0);
            c0 = __builtin_amdgcn_mfma_f32_32x32x16_bf16(a0, blo, c0, 0, 0, 0);
            c1 = __builtin_amdgcn_mfma_f32_32x32x16_bf16(a1, bhi, c1, 0, 0, 0);
            c1 = __builtin_amdgcn_mfma_f32_32x32x16_bf16(a1, blo, c1, 0, 0, 0);
            bhi = bhin; blo = blon;
        }
    }

    // ---- scatter-add into agg[b, dst, col] ----
    #pragma unroll
    for (int r = 0; r < 16; ++r) {
        int row = (r & 3) + 8 * (r >> 2) + 4 * half;
        atomicAdd(agg + ((size_t)b * NC + s_dst[row]) * HID + col, c0[r]);
        atomicAdd(agg + ((size_t)b * NC + s_dst[row + 32]) * HID + col, c1[r]);
    }
}

// 32 nodes/block, 512 threads = 8 waves; wave wv owns n-tile wv, 1 m-tile
__global__ __launch_bounds__(512, 6)
void node_kernel(const float* __restrict__ cell_x,
                 const float* __restrict__ agg,
                 const float* __restrict__ counts,
                 const ushort_t* __restrict__ w1hi, const ushort_t* __restrict__ w1lo,
                 const float* __restrict__ b1,
                 const ushort_t* __restrict__ w2hi, const ushort_t* __restrict__ w2lo,
                 const float* __restrict__ b2,
                 const float* __restrict__ gamma, const float* __restrict__ beta,
                 float* __restrict__ out) {
    __shared__ ushort_t Us[32 * UPAD];   // 33,280 B; overlays: H (32*HPAD), hs fp32 (32*HSF*4 = 33,280)
    __shared__ float s_inv[32];
    float* hs = (float*)Us;

    const int tid = threadIdx.x;
    const int b   = blockIdx.x >> 7;             // 128 blocks per batch
    const int r0  = (blockIdx.x & 127) * 32;

    if (tid < 32) {
        float c = counts[b * NC + r0 + tid];
        s_inv[tid] = 1.0f / fmaxf(c, 1.0f);
    }
    __syncthreads();

    // ---- stage U = [cell_x | agg/cnt] as RNE bf16 ----
    {
        const int row = tid >> 4, c8 = tid & 15;
        const float4* crow = (const float4*)(cell_x + ((size_t)b * NC + r0 + row) * HID);
        const float4* grow = (const float4*)(agg + ((size_t)b * NC + r0 + row) * HID);
        float inv = s_inv[row];
        #pragma unroll
        for (int i = 0; i < 8; ++i) {
            int c = c8 + i * 16;                 // float4 index 0..127
            float4 v;
            if (c < 64) v = crow[c];
            else {
                v = grow[c - 64];
                v.x *= inv; v.y *= inv; v.z *= inv; v.w *= inv;
            }
            *(ushort4*)&Us[row * UPAD + c * 4] =
                make_ushort4(bf16_rne(v.x), bf16_rne(v.y), bf16_rne(v.z), bf16_rne(v.w));
        }
    }
    __syncthreads();

    const int wv = tid >> 6, ln = tid & 63;
    const int m32 = ln & 31, half = ln >> 5;
    const int col = wv * 32 + m32;

    // ---- GEMM1: hidden = relu(U @ uW1 + ub1), K=512, 32 k-steps ----
    f32x16 acc;
    {
        float bias = b1[col];
        #pragma unroll
        for (int r = 0; r < 16; ++r) acc[r] = bias;
    }
    {
        const ushort_t* bph = w1hi + ((size_t)wv * 64 + ln) * 8;
        const ushort_t* bpl = w1lo + ((size_t)wv * 64 + ln) * 8;
        s16x8 bhi = *(const s16x8*)bph;
        s16x8 blo = *(const s16x8*)bpl;
        #pragma unroll 2
        for (int t = 0; t < 32; ++t) {
            int tn1 = (t + 1 < 32) ? t + 1 : 31;
            s16x8 bhin = *(const s16x8*)(bph + (size_t)tn1 * 4096);
            s16x8 blon = *(const s16x8*)(bpl + (size_t)tn1 * 4096);
            s16x8 a = *(const s16x8*)&Us[m32 * UPAD + t * 16 + half * 8];
            acc = __builtin_amdgcn_mfma_f32_32x32x16_bf16(a, bhi, acc, 0, 0, 0);
            acc = __builtin_amdgcn_mfma_f32_32x32x16_bf16(a, blo, acc, 0, 0, 0);
            bhi = bhin; blo = blon;
        }
    }
    __syncthreads();   // U dead; reuse for H

    #pragma unroll
    for (int r = 0; r < 16; ++r) {
        int row = (r & 3) + 8 * (r >> 2) + 4 * half;
        Us[row * HPAD + col] = bf16_rne(fmaxf(acc[r], 0.f));
    }
    __syncthreads();

    // ---- GEMM2: o = hidden @ uW2 + ub2, K=256, 16 k-steps ----
    f32x16 c2;
    {
        float bias = b2[col];
        #pragma unroll
        for (int r = 0; r < 16; ++r) c2[r] = bias;
    }
    {
        const ushort_t* bph = w2hi + ((size_t)wv * 64 + ln) * 8;
        const ushort_t* bpl = w2lo + ((size_t)wv * 64 + ln) * 8;
        s16x8 bhi = *(const s16x8*)bph;
        s16x8 blo = *(const s16x8*)bpl;
        #pragma unroll 2
        for (int t = 0; t < 16; ++t) {
            int tn1 = (t + 1 < 16) ? t + 1 : 15;
            s16x8 bhin = *(const s16x8*)(bph + (size_t)tn1 * 4096);
            s16x8 blon = *(const s16x8*)(bpl + (size_t)tn1 * 4096);
            s16x8 a = *(const s16x8*)&Us[m32 * HPAD + t * 16 + half * 8];
            c2 = __builtin_amdgcn_mfma_f32_32x32x16_bf16(a, bhi, c2, 0, 0, 0);
            c2 = __builtin_amdgcn_mfma_f32_32x32x16_bf16(a, blo, c2, 0, 0, 0);
            bhi = bhin; blo = blon;
        }
    }
    __syncthreads();   // H dead; reuse pool for hs (fp32)

    // ---- residual: h = cell_x + o ----
    #pragma unroll
    for (int r = 0; r < 16; ++r) {
        int row = (r & 3) + 8 * (r >> 2) + 4 * half;
        float cx = cell_x[((size_t)b * NC + r0 + row) * HID + col];
        hs[row * HSF + col] = c2[r] + cx;
    }
    __syncthreads();

    // ---- LayerNorm per row: wave wv handles rows wv*4..+3 ----
    #pragma unroll
    for (int i = 0; i < 4; ++i) {
        int r = wv * 4 + i;
        float v[4];
        float s = 0.f, q = 0.f;
        #pragma unroll
        for (int j = 0; j < 4; ++j) {
            v[j] = hs[r * HSF + ln + 64 * j];
            s += v[j];
            q = fmaf(v[j], v[j], q);
        }
        #pragma unroll
        for (int off = 32; off > 0; off >>= 1) {
            s += __shfl_xor(s, off, 64);
            q += __shfl_xor(q, off, 64);
        }
        float mu = s * (1.0f / HID);
        float var = q * (1.0f / HID) - mu * mu;
        float rs = rsqrtf(var + EPSV);
        float* orow = out + ((size_t)b * NC + r0 + r) * HID;
        #pragma unroll
        for (int j = 0; j < 4; ++j) {
            int c = ln + 64 * j;
            orow[c] = (v[j] - mu) * rs * gamma[c] + beta[c];
        }
    }
}

extern "C" void kernel_launch(void* const* d_in, const int* in_sizes, int n_in,
                              void* d_out, int out_size, void* d_ws, size_t ws_size,
                              hipStream_t stream) {
    const float* cell_x = (const float*)d_in[0];
    const int*   eidx   = (const int*)d_in[1];
    const float* eattr  = (const float*)d_in[2];
    const float* mW1    = (const float*)d_in[3];
    const float* mb1    = (const float*)d_in[4];
    const float* mW2    = (const float*)d_in[5];
    const float* mb2    = (const float*)d_in[6];
    const float* uW1    = (const float*)d_in[7];
    const float* ub1    = (const float*)d_in[8];
    const float* uW2    = (const float*)d_in[9];
    const float* ub2    = (const float*)d_in[10];
    const float* gamma  = (const float*)d_in[11];
    const float* beta   = (const float*)d_in[12];
    float* out = (float*)d_out;

    float* agg    = (float*)d_ws;                        // [B, NC, HID] fp32
    float* counts = agg + (size_t)BSZ * NC * HID;        // [B, NC]
    ushort_t* w1hi = (ushort_t*)(counts + BSZ * NC);     // packed mW1: 320*256
    ushort_t* w1lo = w1hi + KIN * HID;
    ushort_t* w2hi = w1lo + KIN * HID;                   // packed mW2: 256*256
    ushort_t* w2lo = w2hi + HID * HID;
    ushort_t* u1hi = w2lo + HID * HID;                   // packed uW1: 512*256
    ushort_t* u1lo = u1hi + 2 * HID * HID;
    ushort_t* u2hi = u1lo + 2 * HID * HID;               // packed uW2: 256*256
    ushort_t* u2lo = u2hi + HID * HID;

    int n4 = (BSZ * NC * HID + BSZ * NC) / 4;
    zero_kernel<<<512, 256, 0, stream>>>((float4*)d_ws, n4);
    pack_w<<<(KIN / 16 * 8 * 64 + 255) / 256, 256, 0, stream>>>(mW1, KIN, w1hi, w1lo);
    pack_w<<<(HID / 16 * 8 * 64 + 255) / 256, 256, 0, stream>>>(mW2, HID, w2hi, w2lo);
    pack_w<<<(2 * HID / 16 * 8 * 64 + 255) / 256, 256, 0, stream>>>(uW1, 2 * HID, u1hi, u1lo);
    pack_w<<<(HID / 16 * 8 * 64 + 255) / 256, 256, 0, stream>>>(uW2, HID, u2hi, u2lo);
    count_kernel<<<(BSZ * NE) / 256, 256, 0, stream>>>(eidx, counts);
    edge_kernel<<<BSZ * NE / 64, 512, 0, stream>>>(cell_x, eidx, eattr,
                                                   w1hi, w1lo, mb1, w2hi, w2lo, mb2, agg);
    node_kernel<<<BSZ * NC / 32, 512, 0, stream>>>(cell_x, agg, counts,
                                                   u1hi, u1lo, ub1, u2hi, u2lo, ub2,
                                                   gamma, beta, out);
}

// Round 6
// 423.695 us; speedup vs baseline: 6.8681x; 1.0047x over previous
//
#include <hip/hip_runtime.h>

#define HID 256
#define EF  64
#define KIN 320      // HID + EF
#define NC  4096
#define NE  65536
#define BSZ 4
#define EPSV 1e-5f

typedef unsigned short ushort_t;
typedef __attribute__((ext_vector_type(8))) short s16x8;
typedef __attribute__((ext_vector_type(16))) float f32x16;

#define MEB  96      // edges per block (3 m-tiles x 32)
#define EBLK 683     // ceil(NE/MEB)
// LDS strides in ushort elements
#define XPAD 328     // edge X tile row: 656 B
#define HPAD 264     // hidden tile row: 528 B
#define UPAD 520     // node U tile row: 1040 B
#define HSF  260     // node h (fp32) stride

// round-to-nearest-even fp32 -> bf16
__device__ __forceinline__ ushort_t bf16_rne(float f) {
    unsigned u = __float_as_uint(f);
    return (ushort_t)((u + 0x7fffu + ((u >> 16) & 1u)) >> 16);
}
// truncating hi/lo split (pair sums to ~fp32 precision) — for weights (B operand)
__device__ __forceinline__ void split_bf16(float v, ushort_t& h, ushort_t& l) {
    unsigned u = __float_as_uint(v);
    h = (ushort_t)(u >> 16);
    float hf = __uint_as_float(u & 0xffff0000u);
    l = (ushort_t)(__float_as_uint(v - hf) >> 16);
}

__global__ void zero_kernel(float4* __restrict__ p, int n4) {
    int i = blockIdx.x * blockDim.x + threadIdx.x;
    int stride = gridDim.x * blockDim.x;
    float4 z = make_float4(0.f, 0.f, 0.f, 0.f);
    for (; i < n4; i += stride) p[i] = z;
}

// Pack all four weights into 32x32x16 MFMA B-fragment order, hi/lo bf16.
// frag idx = (t*8 + nt)*64 + lane; elem j: W[t*16 + (lane>>5)*8 + j][nt*32 + (lane&31)]
__device__ __forceinline__ void pack_one(const float* W, int idx,
                                         ushort_t* hi, ushort_t* lo) {
    int l = idx & 63;
    int tn = idx >> 6;
    int nt = tn & 7, t = tn >> 3;
    int k0 = t * 16 + (l >> 5) * 8;
    int col = nt * 32 + (l & 31);
    #pragma unroll
    for (int j = 0; j < 8; ++j) {
        float v = W[(size_t)(k0 + j) * 256 + col];
        ushort_t h, lw;
        split_bf16(v, h, lw);
        hi[(size_t)idx * 8 + j] = h;
        lo[(size_t)idx * 8 + j] = lw;
    }
}

#define FR1 10240    // (320/16)*8*64
#define FR2 8192     // (256/16)*8*64
#define FR3 16384    // (512/16)*8*64

__global__ __launch_bounds__(256)
void pack_all(const float* __restrict__ mW1, const float* __restrict__ mW2,
              const float* __restrict__ uW1, const float* __restrict__ uW2,
              ushort_t* __restrict__ w1hi, ushort_t* __restrict__ w1lo,
              ushort_t* __restrict__ w2hi, ushort_t* __restrict__ w2lo,
              ushort_t* __restrict__ u1hi, ushort_t* __restrict__ u1lo,
              ushort_t* __restrict__ u2hi, ushort_t* __restrict__ u2lo) {
    int idx = blockIdx.x * 256 + threadIdx.x;
    if (idx < FR1) { pack_one(mW1, idx, w1hi, w1lo); return; }
    idx -= FR1;
    if (idx < FR2) { pack_one(mW2, idx, w2hi, w2lo); return; }
    idx -= FR2;
    if (idx < FR3) { pack_one(uW1, idx, u1hi, u1lo); return; }
    idx -= FR3;
    if (idx < FR2) { pack_one(uW2, idx, u2hi, u2lo); return; }
}

// 96 edges/block, 512 threads = 8 waves; wave wv owns n-tile wv, 3 m-tiles
__global__ __launch_bounds__(512, 4)
void edge_kernel(const float* __restrict__ cell_x,
                 const int*   __restrict__ eidx,
                 const float* __restrict__ eattr,
                 const ushort_t* __restrict__ w1hi, const ushort_t* __restrict__ w1lo,
                 const float* __restrict__ b1,
                 const ushort_t* __restrict__ w2hi, const ushort_t* __restrict__ w2lo,
                 const float* __restrict__ b2,
                 float* __restrict__ agg, float* __restrict__ counts) {
    __shared__ ushort_t Xs[MEB * XPAD];   // 62,976 B; reused as H (96*HPAD*2 = 50,688 B)
    __shared__ int s_src[MEB], s_dst[MEB];

    const int tid = threadIdx.x;
    const int b   = blockIdx.y;
    const int e0  = blockIdx.x * MEB;
    const int ecnt = min(MEB, NE - e0);

    if (tid < MEB) {
        int e = min(e0 + tid, NE - 1);
        int2 v = ((const int2*)eidx)[(size_t)b * NE + e];
        int sv = min(max(v.x, 0), NC - 1);
        int dv = min(max(v.y, 0), NC - 1);
        s_src[tid] = (tid < ecnt) ? sv : 0;
        s_dst[tid] = dv;
        if (tid < ecnt) atomicAdd(&counts[b * NC + dv], 1.0f);   // fused count
    }
    __syncthreads();

    // ---- stage X = [src_x | edge_attr] as RNE bf16; 16 threads/row, 3 row-groups ----
    {
        const int c8 = tid & 15;
        #pragma unroll
        for (int g = 0; g < 3; ++g) {
            int row = (tid >> 4) + 32 * g;
            const float4* crow = (const float4*)(cell_x + ((size_t)b * NC + s_src[row]) * HID);
            int ea = min(e0 + row, NE - 1);
            const float4* arow = (const float4*)(eattr + ((size_t)b * NE + ea) * EF);
            #pragma unroll
            for (int i = 0; i < 5; ++i) {
                int c = c8 + i * 16;             // float4 index 0..79
                float4 v = (c < 64) ? crow[c] : arow[c - 64];
                *(ushort4*)&Xs[row * XPAD + c * 4] =
                    make_ushort4(bf16_rne(v.x), bf16_rne(v.y), bf16_rne(v.z), bf16_rne(v.w));
            }
        }
    }
    __syncthreads();

    const int wv = tid >> 6, ln = tid & 63;
    const int m32 = ln & 31, half = ln >> 5;
    const int col = wv * 32 + m32;

    // ---- GEMM1: hidden = relu(X @ W1 + b1), K=320, 20 k-steps ----
    f32x16 A0, A1, A2;
    {
        float bias = b1[col];
        #pragma unroll
        for (int r = 0; r < 16; ++r) { A0[r] = bias; A1[r] = bias; A2[r] = bias; }
    }
    {
        const ushort_t* bph = w1hi + ((size_t)wv * 64 + ln) * 8;
        const ushort_t* bpl = w1lo + ((size_t)wv * 64 + ln) * 8;
        s16x8 bh0 = *(const s16x8*)bph;
        s16x8 bl0 = *(const s16x8*)bpl;
        s16x8 bh1 = *(const s16x8*)(bph + 4096);
        s16x8 bl1 = *(const s16x8*)(bpl + 4096);
        for (int t = 0; t < 20; t += 2) {
            // step t (slot 0); prefetch t+2
            s16x8 nh = *(const s16x8*)(bph + (size_t)min(t + 2, 19) * 4096);
            s16x8 nl = *(const s16x8*)(bpl + (size_t)min(t + 2, 19) * 4096);
            int ao = m32 * XPAD + t * 16 + half * 8;
            s16x8 a0 = *(const s16x8*)&Xs[ao];
            s16x8 a1 = *(const s16x8*)&Xs[ao + 32 * XPAD];
            s16x8 a2 = *(const s16x8*)&Xs[ao + 64 * XPAD];
            A0 = __builtin_amdgcn_mfma_f32_32x32x16_bf16(a0, bh0, A0, 0, 0, 0);
            A0 = __builtin_amdgcn_mfma_f32_32x32x16_bf16(a0, bl0, A0, 0, 0, 0);
            A1 = __builtin_amdgcn_mfma_f32_32x32x16_bf16(a1, bh0, A1, 0, 0, 0);
            A1 = __builtin_amdgcn_mfma_f32_32x32x16_bf16(a1, bl0, A1, 0, 0, 0);
            A2 = __builtin_amdgcn_mfma_f32_32x32x16_bf16(a2, bh0, A2, 0, 0, 0);
            A2 = __builtin_amdgcn_mfma_f32_32x32x16_bf16(a2, bl0, A2, 0, 0, 0);
            bh0 = nh; bl0 = nl;
            // step t+1 (slot 1); prefetch t+3
            nh = *(const s16x8*)(bph + (size_t)min(t + 3, 19) * 4096);
            nl = *(const s16x8*)(bpl + (size_t)min(t + 3, 19) * 4096);
            ao = m32 * XPAD + (t + 1) * 16 + half * 8;
            a0 = *(const s16x8*)&Xs[ao];
            a1 = *(const s16x8*)&Xs[ao + 32 * XPAD];
            a2 = *(const s16x8*)&Xs[ao + 64 * XPAD];
            A0 = __builtin_amdgcn_mfma_f32_32x32x16_bf16(a0, bh1, A0, 0, 0, 0);
            A0 = __builtin_amdgcn_mfma_f32_32x32x16_bf16(a0, bl1, A0, 0, 0, 0);
            A1 = __builtin_amdgcn_mfma_f32_32x32x16_bf16(a1, bh1, A1, 0, 0, 0);
            A1 = __builtin_amdgcn_mfma_f32_32x32x16_bf16(a1, bl1, A1, 0, 0, 0);
            A2 = __builtin_amdgcn_mfma_f32_32x32x16_bf16(a2, bh1, A2, 0, 0, 0);
            A2 = __builtin_amdgcn_mfma_f32_32x32x16_bf16(a2, bl1, A2, 0, 0, 0);
            bh1 = nh; bl1 = nl;
        }
    }
    __syncthreads();   // all X reads done; reuse LDS for H

    // ---- relu + RNE bf16 + store hidden (rows = edges) ----
    #pragma unroll
    for (int r = 0; r < 16; ++r) {
        int row = (r & 3) + 8 * (r >> 2) + 4 * half;
        Xs[row * HPAD + col]        = bf16_rne(fmaxf(A0[r], 0.f));
        Xs[(row + 32) * HPAD + col] = bf16_rne(fmaxf(A1[r], 0.f));
        Xs[(row + 64) * HPAD + col] = bf16_rne(fmaxf(A2[r], 0.f));
    }
    __syncthreads();

    // ---- GEMM2: msg = hidden @ W2 + b2, K=256, 16 k-steps ----
    f32x16 C0, C1, C2;
    {
        float bias = b2[col];
        #pragma unroll
        for (int r = 0; r < 16; ++r) { C0[r] = bias; C1[r] = bias; C2[r] = bias; }
    }
    {
        const ushort_t* bph = w2hi + ((size_t)wv * 64 + ln) * 8;
        const ushort_t* bpl = w2lo + ((size_t)wv * 64 + ln) * 8;
        s16x8 bh0 = *(const s16x8*)bph;
        s16x8 bl0 = *(const s16x8*)bpl;
        s16x8 bh1 = *(const s16x8*)(bph + 4096);
        s16x8 bl1 = *(const s16x8*)(bpl + 4096);
        for (int t = 0; t < 16; t += 2) {
            s16x8 nh = *(const s16x8*)(bph + (size_t)min(t + 2, 15) * 4096);
            s16x8 nl = *(const s16x8*)(bpl + (size_t)min(t + 2, 15) * 4096);
            int ao = m32 * HPAD + t * 16 + half * 8;
            s16x8 a0 = *(const s16x8*)&Xs[ao];
            s16x8 a1 = *(const s16x8*)&Xs[ao + 32 * HPAD];
            s16x8 a2 = *(const s16x8*)&Xs[ao + 64 * HPAD];
            C0 = __builtin_amdgcn_mfma_f32_32x32x16_bf16(a0, bh0, C0, 0, 0, 0);
            C0 = __builtin_amdgcn_mfma_f32_32x32x16_bf16(a0, bl0, C0, 0, 0, 0);
            C1 = __builtin_amdgcn_mfma_f32_32x32x16_bf16(a1, bh0, C1, 0, 0, 0);
            C1 = __builtin_amdgcn_mfma_f32_32x32x16_bf16(a1, bl0, C1, 0, 0, 0);
            C2 = __builtin_amdgcn_mfma_f32_32x32x16_bf16(a2, bh0, C2, 0, 0, 0);
            C2 = __builtin_amdgcn_mfma_f32_32x32x16_bf16(a2, bl0, C2, 0, 0, 0);
            bh0 = nh; bl0 = nl;
            nh = *(const s16x8*)(bph + (size_t)min(t + 3, 15) * 4096);
            nl = *(const s16x8*)(bpl + (size_t)min(t + 3, 15) * 4096);
            ao = m32 * HPAD + (t + 1) * 16 + half * 8;
            a0 = *(const s16x8*)&Xs[ao];
            a1 = *(const s16x8*)&Xs[ao + 32 * HPAD];
            a2 = *(const s16x8*)&Xs[ao + 64 * HPAD];
            C0 = __builtin_amdgcn_mfma_f32_32x32x16_bf16(a0, bh1, C0, 0, 0, 0);
            C0 = __builtin_amdgcn_mfma_f32_32x32x16_bf16(a0, bl1, C0, 0, 0, 0);
            C1 = __builtin_amdgcn_mfma_f32_32x32x16_bf16(a1, bh1, C1, 0, 0, 0);
            C1 = __builtin_amdgcn_mfma_f32_32x32x16_bf16(a1, bl1, C1, 0, 0, 0);
            C2 = __builtin_amdgcn_mfma_f32_32x32x16_bf16(a2, bh1, C2, 0, 0, 0);
            C2 = __builtin_amdgcn_mfma_f32_32x32x16_bf16(a2, bl1, C2, 0, 0, 0);
            bh1 = nh; bl1 = nl;
        }
    }

    // ---- scatter-add into agg[b, dst, col] ----
    #pragma unroll
    for (int r = 0; r < 16; ++r) {
        int row = (r & 3) + 8 * (r >> 2) + 4 * half;
        if (row < ecnt)
            atomicAdd(agg + ((size_t)b * NC + s_dst[row]) * HID + col, C0[r]);
        if (row + 32 < ecnt)
            atomicAdd(agg + ((size_t)b * NC + s_dst[row + 32]) * HID + col, C1[r]);
        if (row + 64 < ecnt)
            atomicAdd(agg + ((size_t)b * NC + s_dst[row + 64]) * HID + col, C2[r]);
    }
}

// 32 nodes/block, 512 threads = 8 waves; wave wv owns n-tile wv, 1 m-tile
__global__ __launch_bounds__(512, 6)
void node_kernel(const float* __restrict__ cell_x,
                 const float* __restrict__ agg,
                 const float* __restrict__ counts,
                 const ushort_t* __restrict__ w1hi, const ushort_t* __restrict__ w1lo,
                 const float* __restrict__ b1,
                 const ushort_t* __restrict__ w2hi, const ushort_t* __restrict__ w2lo,
                 const float* __restrict__ b2,
                 const float* __restrict__ gamma, const float* __restrict__ beta,
                 float* __restrict__ out) {
    __shared__ ushort_t Us[32 * UPAD];   // 33,280 B; overlays: H (32*HPAD), hs fp32
    __shared__ float s_inv[32];
    float* hs = (float*)Us;

    const int tid = threadIdx.x;
    const int b   = blockIdx.x >> 7;             // 128 blocks per batch
    const int r0  = (blockIdx.x & 127) * 32;

    if (tid < 32) {
        float c = counts[b * NC + r0 + tid];
        s_inv[tid] = 1.0f / fmaxf(c, 1.0f);
    }
    __syncthreads();

    // ---- stage U = [cell_x | agg/cnt] as RNE bf16 ----
    {
        const int row = tid >> 4, c8 = tid & 15;
        const float4* crow = (const float4*)(cell_x + ((size_t)b * NC + r0 + row) * HID);
        const float4* grow = (const float4*)(agg + ((size_t)b * NC + r0 + row) * HID);
        float inv = s_inv[row];
        #pragma unroll
        for (int i = 0; i < 8; ++i) {
            int c = c8 + i * 16;                 // float4 index 0..127
            float4 v;
            if (c < 64) v = crow[c];
            else {
                v = grow[c - 64];
                v.x *= inv; v.y *= inv; v.z *= inv; v.w *= inv;
            }
            *(ushort4*)&Us[row * UPAD + c * 4] =
                make_ushort4(bf16_rne(v.x), bf16_rne(v.y), bf16_rne(v.z), bf16_rne(v.w));
        }
    }
    __syncthreads();

    const int wv = tid >> 6, ln = tid & 63;
    const int m32 = ln & 31, half = ln >> 5;
    const int col = wv * 32 + m32;

    // ---- GEMM1: hidden = relu(U @ uW1 + ub1), K=512, 32 k-steps ----
    f32x16 acc;
    {
        float bias = b1[col];
        #pragma unroll
        for (int r = 0; r < 16; ++r) acc[r] = bias;
    }
    {
        const ushort_t* bph = w1hi + ((size_t)wv * 64 + ln) * 8;
        const ushort_t* bpl = w1lo + ((size_t)wv * 64 + ln) * 8;
        s16x8 bhi = *(const s16x8*)bph;
        s16x8 blo = *(const s16x8*)bpl;
        #pragma unroll 2
        for (int t = 0; t < 32; ++t) {
            int tn1 = (t + 1 < 32) ? t + 1 : 31;
            s16x8 bhin = *(const s16x8*)(bph + (size_t)tn1 * 4096);
            s16x8 blon = *(const s16x8*)(bpl + (size_t)tn1 * 4096);
            s16x8 a = *(const s16x8*)&Us[m32 * UPAD + t * 16 + half * 8];
            acc = __builtin_amdgcn_mfma_f32_32x32x16_bf16(a, bhi, acc, 0, 0, 0);
            acc = __builtin_amdgcn_mfma_f32_32x32x16_bf16(a, blo, acc, 0, 0, 0);
            bhi = bhin; blo = blon;
        }
    }
    __syncthreads();   // U dead; reuse for H

    #pragma unroll
    for (int r = 0; r < 16; ++r) {
        int row = (r & 3) + 8 * (r >> 2) + 4 * half;
        Us[row * HPAD + col] = bf16_rne(fmaxf(acc[r], 0.f));
    }
    __syncthreads();

    // ---- GEMM2: o = hidden @ uW2 + ub2, K=256, 16 k-steps ----
    f32x16 c2;
    {
        float bias = b2[col];
        #pragma unroll
        for (int r = 0; r < 16; ++r) c2[r] = bias;
    }
    {
        const ushort_t* bph = w2hi + ((size_t)wv * 64 + ln) * 8;
        const ushort_t* bpl = w2lo + ((size_t)wv * 64 + ln) * 8;
        s16x8 bhi = *(const s16x8*)bph;
        s16x8 blo = *(const s16x8*)bpl;
        #pragma unroll 2
        for (int t = 0; t < 16; ++t) {
            int tn1 = (t + 1 < 16) ? t + 1 : 15;
            s16x8 bhin = *(const s16x8*)(bph + (size_t)tn1 * 4096);
            s16x8 blon = *(const s16x8*)(bpl + (size_t)tn1 * 4096);
            s16x8 a = *(const s16x8*)&Us[m32 * HPAD + t * 16 + half * 8];
            c2 = __builtin_amdgcn_mfma_f32_32x32x16_bf16(a, bhi, c2, 0, 0, 0);
            c2 = __builtin_amdgcn_mfma_f32_32x32x16_bf16(a, blo, c2, 0, 0, 0);
            bhi = bhin; blo = blon;
        }
    }
    __syncthreads();   // H dead; reuse pool for hs (fp32)

    // ---- residual: h = cell_x + o ----
    #pragma unroll
    for (int r = 0; r < 16; ++r) {
        int row = (r & 3) + 8 * (r >> 2) + 4 * half;
        float cx = cell_x[((size_t)b * NC + r0 + row) * HID + col];
        hs[row * HSF + col] = c2[r] + cx;
    }
    __syncthreads();

    // ---- LayerNorm per row: wave wv handles rows wv*4..+3 ----
    #pragma unroll
    for (int i = 0; i < 4; ++i) {
        int r = wv * 4 + i;
        float v[4];
        float s = 0.f, q = 0.f;
        #pragma unroll
        for (int j = 0; j < 4; ++j) {
            v[j] = hs[r * HSF + ln + 64 * j];
            s += v[j];
            q = fmaf(v[j], v[j], q);
        }
        #pragma unroll
        for (int off = 32; off > 0; off >>= 1) {
            s += __shfl_xor(s, off, 64);
            q += __shfl_xor(q, off, 64);
        }
        float mu = s * (1.0f / HID);
        float var = q * (1.0f / HID) - mu * mu;
        float rs = rsqrtf(var + EPSV);
        float* orow = out + ((size_t)b * NC + r0 + r) * HID;
        #pragma unroll
        for (int j = 0; j < 4; ++j) {
            int c = ln + 64 * j;
            orow[c] = (v[j] - mu) * rs * gamma[c] + beta[c];
        }
    }
}

extern "C" void kernel_launch(void* const* d_in, const int* in_sizes, int n_in,
                              void* d_out, int out_size, void* d_ws, size_t ws_size,
                              hipStream_t stream) {
    const float* cell_x = (const float*)d_in[0];
    const int*   eidx   = (const int*)d_in[1];
    const float* eattr  = (const float*)d_in[2];
    const float* mW1    = (const float*)d_in[3];
    const float* mb1    = (const float*)d_in[4];
    const float* mW2    = (const float*)d_in[5];
    const float* mb2    = (const float*)d_in[6];
    const float* uW1    = (const float*)d_in[7];
    const float* ub1    = (const float*)d_in[8];
    const float* uW2    = (const float*)d_in[9];
    const float* ub2    = (const float*)d_in[10];
    const float* gamma  = (const float*)d_in[11];
    const float* beta   = (const float*)d_in[12];
    float* out = (float*)d_out;

    float* agg    = (float*)d_ws;                        // [B, NC, HID] fp32
    float* counts = agg + (size_t)BSZ * NC * HID;        // [B, NC]
    ushort_t* w1hi = (ushort_t*)(counts + BSZ * NC);     // packed mW1: 320*256
    ushort_t* w1lo = w1hi + KIN * HID;
    ushort_t* w2hi = w1lo + KIN * HID;                   // packed mW2: 256*256
    ushort_t* w2lo = w2hi + HID * HID;
    ushort_t* u1hi = w2lo + HID * HID;                   // packed uW1: 512*256
    ushort_t* u1lo = u1hi + 2 * HID * HID;
    ushort_t* u2hi = u1lo + 2 * HID * HID;               // packed uW2: 256*256
    ushort_t* u2lo = u2hi + HID * HID;

    int n4 = (BSZ * NC * HID + BSZ * NC) / 4;
    zero_kernel<<<512, 256, 0, stream>>>((float4*)d_ws, n4);
    pack_all<<<(FR1 + FR2 + FR3 + FR2 + 255) / 256, 256, 0, stream>>>(
        mW1, mW2, uW1, uW2, w1hi, w1lo, w2hi, w2lo, u1hi, u1lo, u2hi, u2lo);
    edge_kernel<<<dim3(EBLK, BSZ), 512, 0, stream>>>(cell_x, eidx, eattr,
                                                     w1hi, w1lo, mb1, w2hi, w2lo, mb2,
                                                     agg, counts);
    node_kernel<<<BSZ * NC / 32, 512, 0, stream>>>(cell_x, agg, counts,
                                                   u1hi, u1lo, ub1, u2hi, u2lo, ub2,
                                                   gamma, beta, out);
}

// Round 7
// 341.907 us; speedup vs baseline: 8.5110x; 1.2392x over previous
//
#include <hip/hip_runtime.h>

#define HID 256
#define EF  64
#define KIN 320      // HID + EF
#define NC  4096
#define NE  65536
#define BSZ 4
#define EPSV 1e-5f

typedef unsigned short ushort_t;
typedef __attribute__((ext_vector_type(8))) short s16x8;
typedef __attribute__((ext_vector_type(16))) float f32x16;

// LDS strides in ushort elements
#define XPAD 328     // edge X tile row: 656 B
#define HPAD 264     // hidden tile row: 528 B
#define UPAD 520     // node U tile row: 1040 B
#define HSF  260     // node h (fp32) stride

// round-to-nearest-even fp32 -> bf16 (as ushort bits)
__device__ __forceinline__ ushort_t bf16_rne(float f) {
    unsigned u = __float_as_uint(f);
    return (ushort_t)((u + 0x7fffu + ((u >> 16) & 1u)) >> 16);
}
__device__ __forceinline__ float bf16_to_f(ushort_t u) {
    return __uint_as_float(((unsigned)u) << 16);
}
// truncating hi/lo split (pair sums to ~fp32 precision) — for weights (B operand)
__device__ __forceinline__ void split_bf16(float v, ushort_t& h, ushort_t& l) {
    unsigned u = __float_as_uint(v);
    h = (ushort_t)(u >> 16);
    float hf = __uint_as_float(u & 0xffff0000u);
    l = (ushort_t)(__float_as_uint(v - hf) >> 16);
}

__global__ void zero_kernel(float4* __restrict__ p, int n4) {
    int i = blockIdx.x * blockDim.x + threadIdx.x;
    int stride = gridDim.x * blockDim.x;
    float4 z = make_float4(0.f, 0.f, 0.f, 0.f);
    for (; i < n4; i += stride) p[i] = z;
}

// Pack weights into 32x32x16 MFMA B-fragment order, hi/lo bf16.
// frag idx = (t*8 + nt)*64 + lane; elem j: W[t*16 + (lane>>5)*8 + j][nt*32 + (lane&31)]
__device__ __forceinline__ void pack_one(const float* W, int idx,
                                         ushort_t* hi, ushort_t* lo) {
    int l = idx & 63;
    int tn = idx >> 6;
    int nt = tn & 7, t = tn >> 3;
    int k0 = t * 16 + (l >> 5) * 8;
    int col = nt * 32 + (l & 31);
    #pragma unroll
    for (int j = 0; j < 8; ++j) {
        float v = W[(size_t)(k0 + j) * 256 + col];
        ushort_t h, lw;
        split_bf16(v, h, lw);
        hi[(size_t)idx * 8 + j] = h;
        lo[(size_t)idx * 8 + j] = lw;
    }
}

#define FR1 10240    // (320/16)*8*64
#define FR2 8192     // (256/16)*8*64
#define FR3 16384    // (512/16)*8*64

__global__ __launch_bounds__(256)
void pack_all(const float* __restrict__ mW1, const float* __restrict__ mW2,
              const float* __restrict__ uW1, const float* __restrict__ uW2,
              ushort_t* __restrict__ w1hi, ushort_t* __restrict__ w1lo,
              ushort_t* __restrict__ w2hi, ushort_t* __restrict__ w2lo,
              ushort_t* __restrict__ u1hi, ushort_t* __restrict__ u1lo,
              ushort_t* __restrict__ u2hi, ushort_t* __restrict__ u2lo) {
    int idx = blockIdx.x * 256 + threadIdx.x;
    if (idx < FR1) { pack_one(mW1, idx, w1hi, w1lo); return; }
    idx -= FR1;
    if (idx < FR2) { pack_one(mW2, idx, w2hi, w2lo); return; }
    idx -= FR2;
    if (idx < FR3) { pack_one(uW1, idx, u1hi, u1lo); return; }
    idx -= FR3;
    if (idx < FR2) { pack_one(uW2, idx, u2hi, u2lo); return; }
}

// 64 edges/block, 512 threads = 8 waves; wave wv owns n-tile wv, 2 m-tiles
__global__ __launch_bounds__(512, 6)
void edge_kernel(const float* __restrict__ cell_x,
                 const int*   __restrict__ eidx,
                 const float* __restrict__ eattr,
                 const ushort_t* __restrict__ w1hi, const ushort_t* __restrict__ w1lo,
                 const float* __restrict__ b1,
                 const ushort_t* __restrict__ w2hi, const ushort_t* __restrict__ w2lo,
                 const float* __restrict__ b2,
                 ushort_t* __restrict__ aggbf, float* __restrict__ counts) {
    __shared__ ushort_t Xs[64 * XPAD];   // 41,984 B; reused as H (64*HPAD*2 = 33,792 B)
    __shared__ int s_src[64], s_dst[64];

    const int tid = threadIdx.x;
    const int b   = blockIdx.x >> 10;            // 1024 blocks per batch
    const int e0  = (blockIdx.x & 1023) * 64;

    if (tid < 64) {
        int2 v = ((const int2*)eidx)[(size_t)b * NE + e0 + tid];
        int dv = min(max(v.y, 0), NC - 1);
        s_src[tid] = min(max(v.x, 0), NC - 1);
        s_dst[tid] = dv;
        atomicAdd(&counts[b * NC + dv], 1.0f);   // fused degree count
    }
    __syncthreads();

    // ---- stage X = [src_x | edge_attr] as RNE bf16 ----
    {
        const int row = tid >> 3, c8 = tid & 7;
        const float4* crow = (const float4*)(cell_x + ((size_t)b * NC + s_src[row]) * HID);
        const float4* arow = (const float4*)(eattr + ((size_t)b * NE + e0 + row) * EF);
        #pragma unroll
        for (int i = 0; i < 10; ++i) {
            int c = c8 + i * 8;                  // float4 index 0..79
            float4 v = (c < 64) ? crow[c] : arow[c - 64];
            *(ushort4*)&Xs[row * XPAD + c * 4] =
                make_ushort4(bf16_rne(v.x), bf16_rne(v.y), bf16_rne(v.z), bf16_rne(v.w));
        }
    }
    __syncthreads();

    const int wv = tid >> 6, ln = tid & 63;
    const int m32 = ln & 31, half = ln >> 5;
    const int col = wv * 32 + m32;

    // ---- GEMM1: hidden = relu(X @ W1 + b1), K=320, 20 k-steps ----
    f32x16 A0, A1;
    {
        float bias = b1[col];
        #pragma unroll
        for (int r = 0; r < 16; ++r) { A0[r] = bias; A1[r] = bias; }
    }
    {
        const ushort_t* bph = w1hi + ((size_t)wv * 64 + ln) * 8;
        const ushort_t* bpl = w1lo + ((size_t)wv * 64 + ln) * 8;
        s16x8 bh0 = *(const s16x8*)bph;
        s16x8 bl0 = *(const s16x8*)bpl;
        s16x8 bh1 = *(const s16x8*)(bph + 4096);
        s16x8 bl1 = *(const s16x8*)(bpl + 4096);
        for (int t = 0; t < 20; t += 2) {
            s16x8 nh = *(const s16x8*)(bph + (size_t)min(t + 2, 19) * 4096);
            s16x8 nl = *(const s16x8*)(bpl + (size_t)min(t + 2, 19) * 4096);
            int ao = m32 * XPAD + t * 16 + half * 8;
            s16x8 a0 = *(const s16x8*)&Xs[ao];
            s16x8 a1 = *(const s16x8*)&Xs[ao + 32 * XPAD];
            A0 = __builtin_amdgcn_mfma_f32_32x32x16_bf16(a0, bh0, A0, 0, 0, 0);
            A0 = __builtin_amdgcn_mfma_f32_32x32x16_bf16(a0, bl0, A0, 0, 0, 0);
            A1 = __builtin_amdgcn_mfma_f32_32x32x16_bf16(a1, bh0, A1, 0, 0, 0);
            A1 = __builtin_amdgcn_mfma_f32_32x32x16_bf16(a1, bl0, A1, 0, 0, 0);
            bh0 = nh; bl0 = nl;
            nh = *(const s16x8*)(bph + (size_t)min(t + 3, 19) * 4096);
            nl = *(const s16x8*)(bpl + (size_t)min(t + 3, 19) * 4096);
            ao = m32 * XPAD + (t + 1) * 16 + half * 8;
            a0 = *(const s16x8*)&Xs[ao];
            a1 = *(const s16x8*)&Xs[ao + 32 * XPAD];
            A0 = __builtin_amdgcn_mfma_f32_32x32x16_bf16(a0, bh1, A0, 0, 0, 0);
            A0 = __builtin_amdgcn_mfma_f32_32x32x16_bf16(a0, bl1, A0, 0, 0, 0);
            A1 = __builtin_amdgcn_mfma_f32_32x32x16_bf16(a1, bh1, A1, 0, 0, 0);
            A1 = __builtin_amdgcn_mfma_f32_32x32x16_bf16(a1, bl1, A1, 0, 0, 0);
            bh1 = nh; bl1 = nl;
        }
    }
    __syncthreads();   // all X reads done; reuse LDS for H

    // ---- relu + RNE bf16 + store hidden (rows = edges) ----
    #pragma unroll
    for (int r = 0; r < 16; ++r) {
        int row = (r & 3) + 8 * (r >> 2) + 4 * half;
        Xs[row * HPAD + col]        = bf16_rne(fmaxf(A0[r], 0.f));
        Xs[(row + 32) * HPAD + col] = bf16_rne(fmaxf(A1[r], 0.f));
    }
    __syncthreads();

    // ---- GEMM2: msg = hidden @ W2 + b2, K=256, 16 k-steps ----
    f32x16 C0, C1;
    {
        float bias = b2[col];
        #pragma unroll
        for (int r = 0; r < 16; ++r) { C0[r] = bias; C1[r] = bias; }
    }
    {
        const ushort_t* bph = w2hi + ((size_t)wv * 64 + ln) * 8;
        const ushort_t* bpl = w2lo + ((size_t)wv * 64 + ln) * 8;
        s16x8 bh0 = *(const s16x8*)bph;
        s16x8 bl0 = *(const s16x8*)bpl;
        s16x8 bh1 = *(const s16x8*)(bph + 4096);
        s16x8 bl1 = *(const s16x8*)(bpl + 4096);
        for (int t = 0; t < 16; t += 2) {
            s16x8 nh = *(const s16x8*)(bph + (size_t)min(t + 2, 15) * 4096);
            s16x8 nl = *(const s16x8*)(bpl + (size_t)min(t + 2, 15) * 4096);
            int ao = m32 * HPAD + t * 16 + half * 8;
            s16x8 a0 = *(const s16x8*)&Xs[ao];
            s16x8 a1 = *(const s16x8*)&Xs[ao + 32 * HPAD];
            C0 = __builtin_amdgcn_mfma_f32_32x32x16_bf16(a0, bh0, C0, 0, 0, 0);
            C0 = __builtin_amdgcn_mfma_f32_32x32x16_bf16(a0, bl0, C0, 0, 0, 0);
            C1 = __builtin_amdgcn_mfma_f32_32x32x16_bf16(a1, bh0, C1, 0, 0, 0);
            C1 = __builtin_amdgcn_mfma_f32_32x32x16_bf16(a1, bl0, C1, 0, 0, 0);
            bh0 = nh; bl0 = nl;
            nh = *(const s16x8*)(bph + (size_t)min(t + 3, 15) * 4096);
            nl = *(const s16x8*)(bpl + (size_t)min(t + 3, 15) * 4096);
            ao = m32 * HPAD + (t + 1) * 16 + half * 8;
            a0 = *(const s16x8*)&Xs[ao];
            a1 = *(const s16x8*)&Xs[ao + 32 * HPAD];
            C0 = __builtin_amdgcn_mfma_f32_32x32x16_bf16(a0, bh1, C0, 0, 0, 0);
            C0 = __builtin_amdgcn_mfma_f32_32x32x16_bf16(a0, bl1, C0, 0, 0, 0);
            C1 = __builtin_amdgcn_mfma_f32_32x32x16_bf16(a1, bh1, C1, 0, 0, 0);
            C1 = __builtin_amdgcn_mfma_f32_32x32x16_bf16(a1, bl1, C1, 0, 0, 0);
            bh1 = nh; bl1 = nl;
        }
    }

    // ---- packed bf16 scatter-add into aggbf[b, dst, col&~1 .. +1] ----
    // lane pair (m32, m32^1) covers cols (colbase, colbase+1); one pk-atomic per pair.
    const int colbase = col & ~1;
    const bool evenl = (m32 & 1) == 0;
    #pragma unroll
    for (int r = 0; r < 16; ++r) {
        int row = (r & 3) + 8 * (r >> 2) + 4 * half;
        {
            float other = __shfl_xor(C0[r], 1, 64);
            float vlo = evenl ? C0[r] : other;
            float vhi = evenl ? other : C0[r];
            if (evenl == (r < 8)) {
                unsigned pk = ((unsigned)bf16_rne(vhi) << 16) | (unsigned)bf16_rne(vlo);
                ushort_t* addr = aggbf + ((size_t)b * NC + s_dst[row]) * HID + colbase;
                asm volatile("global_atomic_pk_add_bf16 %0, %1, off"
                             :: "v"(addr), "v"(pk) : "memory");
            }
        }
        {
            float other = __shfl_xor(C1[r], 1, 64);
            float vlo = evenl ? C1[r] : other;
            float vhi = evenl ? other : C1[r];
            if (evenl == (r < 8)) {
                unsigned pk = ((unsigned)bf16_rne(vhi) << 16) | (unsigned)bf16_rne(vlo);
                ushort_t* addr = aggbf + ((size_t)b * NC + s_dst[row + 32]) * HID + colbase;
                asm volatile("global_atomic_pk_add_bf16 %0, %1, off"
                             :: "v"(addr), "v"(pk) : "memory");
            }
        }
    }
}

// 32 nodes/block, 512 threads = 8 waves; wave wv owns n-tile wv, 1 m-tile
__global__ __launch_bounds__(512, 6)
void node_kernel(const float* __restrict__ cell_x,
                 const ushort_t* __restrict__ aggbf,
                 const float* __restrict__ counts,
                 const ushort_t* __restrict__ w1hi, const ushort_t* __restrict__ w1lo,
                 const float* __restrict__ b1,
                 const ushort_t* __restrict__ w2hi, const ushort_t* __restrict__ w2lo,
                 const float* __restrict__ b2,
                 const float* __restrict__ gamma, const float* __restrict__ beta,
                 float* __restrict__ out) {
    __shared__ ushort_t Us[32 * UPAD];   // 33,280 B; overlays: H (32*HPAD), hs fp32
    __shared__ float s_inv[32];
    float* hs = (float*)Us;

    const int tid = threadIdx.x;
    const int b   = blockIdx.x >> 7;             // 128 blocks per batch
    const int r0  = (blockIdx.x & 127) * 32;

    if (tid < 32) {
        float c = counts[b * NC + r0 + tid];
        s_inv[tid] = 1.0f / fmaxf(c, 1.0f);
    }
    __syncthreads();

    // ---- stage U = [cell_x | aggbf/cnt] as RNE bf16 ----
    {
        const int row = tid >> 4, c8 = tid & 15;
        const float4* crow = (const float4*)(cell_x + ((size_t)b * NC + r0 + row) * HID);
        const ushort4* grow = (const ushort4*)(aggbf + ((size_t)b * NC + r0 + row) * HID);
        float inv = s_inv[row];
        #pragma unroll
        for (int i = 0; i < 8; ++i) {
            int c = c8 + i * 16;                 // 4-elem group index 0..127
            if (c < 64) {
                float4 v = crow[c];
                *(ushort4*)&Us[row * UPAD + c * 4] =
                    make_ushort4(bf16_rne(v.x), bf16_rne(v.y), bf16_rne(v.z), bf16_rne(v.w));
            } else {
                ushort4 g = grow[c - 64];
                *(ushort4*)&Us[row * UPAD + c * 4] =
                    make_ushort4(bf16_rne(bf16_to_f(g.x) * inv),
                                 bf16_rne(bf16_to_f(g.y) * inv),
                                 bf16_rne(bf16_to_f(g.z) * inv),
                                 bf16_rne(bf16_to_f(g.w) * inv));
            }
        }
    }
    __syncthreads();

    const int wv = tid >> 6, ln = tid & 63;
    const int m32 = ln & 31, half = ln >> 5;
    const int col = wv * 32 + m32;

    // ---- GEMM1: hidden = relu(U @ uW1 + ub1), K=512, 32 k-steps ----
    f32x16 acc;
    {
        float bias = b1[col];
        #pragma unroll
        for (int r = 0; r < 16; ++r) acc[r] = bias;
    }
    {
        const ushort_t* bph = w1hi + ((size_t)wv * 64 + ln) * 8;
        const ushort_t* bpl = w1lo + ((size_t)wv * 64 + ln) * 8;
        s16x8 bhi = *(const s16x8*)bph;
        s16x8 blo = *(const s16x8*)bpl;
        #pragma unroll 2
        for (int t = 0; t < 32; ++t) {
            int tn1 = (t + 1 < 32) ? t + 1 : 31;
            s16x8 bhin = *(const s16x8*)(bph + (size_t)tn1 * 4096);
            s16x8 blon = *(const s16x8*)(bpl + (size_t)tn1 * 4096);
            s16x8 a = *(const s16x8*)&Us[m32 * UPAD + t * 16 + half * 8];
            acc = __builtin_amdgcn_mfma_f32_32x32x16_bf16(a, bhi, acc, 0, 0, 0);
            acc = __builtin_amdgcn_mfma_f32_32x32x16_bf16(a, blo, acc, 0, 0, 0);
            bhi = bhin; blo = blon;
        }
    }
    __syncthreads();   // U dead; reuse for H

    #pragma unroll
    for (int r = 0; r < 16; ++r) {
        int row = (r & 3) + 8 * (r >> 2) + 4 * half;
        Us[row * HPAD + col] = bf16_rne(fmaxf(acc[r], 0.f));
    }
    __syncthreads();

    // ---- GEMM2: o = hidden @ uW2 + ub2, K=256, 16 k-steps ----
    f32x16 c2;
    {
        float bias = b2[col];
        #pragma unroll
        for (int r = 0; r < 16; ++r) c2[r] = bias;
    }
    {
        const ushort_t* bph = w2hi + ((size_t)wv * 64 + ln) * 8;
        const ushort_t* bpl = w2lo + ((size_t)wv * 64 + ln) * 8;
        s16x8 bhi = *(const s16x8*)bph;
        s16x8 blo = *(const s16x8*)bpl;
        #pragma unroll 2
        for (int t = 0; t < 16; ++t) {
            int tn1 = (t + 1 < 16) ? t + 1 : 15;
            s16x8 bhin = *(const s16x8*)(bph + (size_t)tn1 * 4096);
            s16x8 blon = *(const s16x8*)(bpl + (size_t)tn1 * 4096);
            s16x8 a = *(const s16x8*)&Us[m32 * HPAD + t * 16 + half * 8];
            c2 = __builtin_amdgcn_mfma_f32_32x32x16_bf16(a, bhi, c2, 0, 0, 0);
            c2 = __builtin_amdgcn_mfma_f32_32x32x16_bf16(a, blo, c2, 0, 0, 0);
            bhi = bhin; blo = blon;
        }
    }
    __syncthreads();   // H dead; reuse pool for hs (fp32)

    // ---- residual: h = cell_x + o ----
    #pragma unroll
    for (int r = 0; r < 16; ++r) {
        int row = (r & 3) + 8 * (r >> 2) + 4 * half;
        float cx = cell_x[((size_t)b * NC + r0 + row) * HID + col];
        hs[row * HSF + col] = c2[r] + cx;
    }
    __syncthreads();

    // ---- LayerNorm per row: wave wv handles rows wv*4..+3 ----
    #pragma unroll
    for (int i = 0; i < 4; ++i) {
        int r = wv * 4 + i;
        float v[4];
        float s = 0.f, q = 0.f;
        #pragma unroll
        for (int j = 0; j < 4; ++j) {
            v[j] = hs[r * HSF + ln + 64 * j];
            s += v[j];
            q = fmaf(v[j], v[j], q);
        }
        #pragma unroll
        for (int off = 32; off > 0; off >>= 1) {
            s += __shfl_xor(s, off, 64);
            q += __shfl_xor(q, off, 64);
        }
        float mu = s * (1.0f / HID);
        float var = q * (1.0f / HID) - mu * mu;
        float rs = rsqrtf(var + EPSV);
        float* orow = out + ((size_t)b * NC + r0 + r) * HID;
        #pragma unroll
        for (int j = 0; j < 4; ++j) {
            int c = ln + 64 * j;
            orow[c] = (v[j] - mu) * rs * gamma[c] + beta[c];
        }
    }
}

extern "C" void kernel_launch(void* const* d_in, const int* in_sizes, int n_in,
                              void* d_out, int out_size, void* d_ws, size_t ws_size,
                              hipStream_t stream) {
    const float* cell_x = (const float*)d_in[0];
    const int*   eidx   = (const int*)d_in[1];
    const float* eattr  = (const float*)d_in[2];
    const float* mW1    = (const float*)d_in[3];
    const float* mb1    = (const float*)d_in[4];
    const float* mW2    = (const float*)d_in[5];
    const float* mb2    = (const float*)d_in[6];
    const float* uW1    = (const float*)d_in[7];
    const float* ub1    = (const float*)d_in[8];
    const float* uW2    = (const float*)d_in[9];
    const float* ub2    = (const float*)d_in[10];
    const float* gamma  = (const float*)d_in[11];
    const float* beta   = (const float*)d_in[12];
    float* out = (float*)d_out;

    ushort_t* aggbf = (ushort_t*)d_ws;                   // [B, NC, HID] bf16 (8 MB)
    float* counts = (float*)(aggbf + (size_t)BSZ * NC * HID);   // [B, NC]
    ushort_t* w1hi = (ushort_t*)(counts + BSZ * NC);     // packed mW1: 320*256
    ushort_t* w1lo = w1hi + KIN * HID;
    ushort_t* w2hi = w1lo + KIN * HID;                   // packed mW2: 256*256
    ushort_t* w2lo = w2hi + HID * HID;
    ushort_t* u1hi = w2lo + HID * HID;                   // packed uW1: 512*256
    ushort_t* u1lo = u1hi + 2 * HID * HID;
    ushort_t* u2hi = u1lo + 2 * HID * HID;               // packed uW2: 256*256
    ushort_t* u2lo = u2hi + HID * HID;

    // zero aggbf (bf16) + counts (fp32): bytes = B*NC*HID*2 + B*NC*4
    int n4 = (BSZ * NC * HID * 2 + BSZ * NC * 4) / 16;
    zero_kernel<<<512, 256, 0, stream>>>((float4*)d_ws, n4);
    pack_all<<<(FR1 + FR2 + FR3 + FR2 + 255) / 256, 256, 0, stream>>>(
        mW1, mW2, uW1, uW2, w1hi, w1lo, w2hi, w2lo, u1hi, u1lo, u2hi, u2lo);
    edge_kernel<<<BSZ * NE / 64, 512, 0, stream>>>(cell_x, eidx, eattr,
                                                   w1hi, w1lo, mb1, w2hi, w2lo, mb2,
                                                   aggbf, counts);
    node_kernel<<<BSZ * NC / 32, 512, 0, stream>>>(cell_x, aggbf, counts,
                                                   u1hi, u1lo, ub1, u2hi, u2lo, ub2,
                                                   gamma, beta, out);
}

// Round 8
// 330.264 us; speedup vs baseline: 8.8111x; 1.0353x over previous
//
#include <hip/hip_runtime.h>

#define HID 256
#define EF  64
#define KIN 320      // HID + EF
#define NC  4096
#define NE  65536
#define BSZ 4
#define EPSV 1e-5f

typedef unsigned short ushort_t;
typedef __attribute__((ext_vector_type(8))) short s16x8;
typedef __attribute__((ext_vector_type(16))) float f32x16;

// LDS strides in ushort elements
#define XPAD 328     // edge X tile row: 656 B
#define HPAD 264     // hidden tile row: 528 B
#define UPAD 520     // node U tile row: 1040 B
#define HSF  260     // node h (fp32) stride

// round-to-nearest-even fp32 -> bf16 (as ushort bits)
__device__ __forceinline__ ushort_t bf16_rne(float f) {
    unsigned u = __float_as_uint(f);
    return (ushort_t)((u + 0x7fffu + ((u >> 16) & 1u)) >> 16);
}
__device__ __forceinline__ float bf16_to_f(ushort_t u) {
    return __uint_as_float(((unsigned)u) << 16);
}
// truncating hi/lo split (pair sums to ~fp32 precision) — for weights (B operand)
__device__ __forceinline__ void split_bf16(float v, ushort_t& h, ushort_t& l) {
    unsigned u = __float_as_uint(v);
    h = (ushort_t)(u >> 16);
    float hf = __uint_as_float(u & 0xffff0000u);
    l = (ushort_t)(__float_as_uint(v - hf) >> 16);
}

// Pack weights into 32x32x16 MFMA B-fragment order, hi/lo bf16.
// frag idx = (t*8 + nt)*64 + lane; elem j: W[t*16 + (lane>>5)*8 + j][nt*32 + (lane&31)]
__device__ __forceinline__ void pack_one(const float* W, int idx,
                                         ushort_t* hi, ushort_t* lo) {
    int l = idx & 63;
    int tn = idx >> 6;
    int nt = tn & 7, t = tn >> 3;
    int k0 = t * 16 + (l >> 5) * 8;
    int col = nt * 32 + (l & 31);
    #pragma unroll
    for (int j = 0; j < 8; ++j) {
        float v = W[(size_t)(k0 + j) * 256 + col];
        ushort_t h, lw;
        split_bf16(v, h, lw);
        hi[(size_t)idx * 8 + j] = h;
        lo[(size_t)idx * 8 + j] = lw;
    }
}

#define FR1 10240    // (320/16)*8*64
#define FR2 8192     // (256/16)*8*64
#define FR3 16384    // (512/16)*8*64
#define PACKB 168    // ceil((FR1+2*FR2+FR3)/256) = 43008/256
#define ZEROB 256    // blocks for the zero path

// blocks [0,PACKB): pack weights; blocks [PACKB, PACKB+ZEROB): zero aggbf+counts
__global__ __launch_bounds__(256)
void prep_kernel(const float* __restrict__ mW1, const float* __restrict__ mW2,
                 const float* __restrict__ uW1, const float* __restrict__ uW2,
                 ushort_t* __restrict__ w1hi, ushort_t* __restrict__ w1lo,
                 ushort_t* __restrict__ w2hi, ushort_t* __restrict__ w2lo,
                 ushort_t* __restrict__ u1hi, ushort_t* __restrict__ u1lo,
                 ushort_t* __restrict__ u2hi, ushort_t* __restrict__ u2lo,
                 float4* __restrict__ zp, int n4) {
    if (blockIdx.x >= PACKB) {
        int i = (blockIdx.x - PACKB) * 256 + threadIdx.x;
        int stride = ZEROB * 256;
        float4 z = make_float4(0.f, 0.f, 0.f, 0.f);
        for (; i < n4; i += stride) zp[i] = z;
        return;
    }
    int idx = blockIdx.x * 256 + threadIdx.x;
    if (idx < FR1) { pack_one(mW1, idx, w1hi, w1lo); return; }
    idx -= FR1;
    if (idx < FR2) { pack_one(mW2, idx, w2hi, w2lo); return; }
    idx -= FR2;
    if (idx < FR3) { pack_one(uW1, idx, u1hi, u1lo); return; }
    idx -= FR3;
    if (idx < FR2) { pack_one(uW2, idx, u2hi, u2lo); return; }
}

// 64 edges/block, 512 threads = 8 waves; wave wv owns n-tile wv, 2 m-tiles
__global__ __launch_bounds__(512, 6)
void edge_kernel(const float* __restrict__ cell_x,
                 const int*   __restrict__ eidx,
                 const float* __restrict__ eattr,
                 const ushort_t* __restrict__ w1hi, const ushort_t* __restrict__ w1lo,
                 const float* __restrict__ b1,
                 const ushort_t* __restrict__ w2hi, const ushort_t* __restrict__ w2lo,
                 const float* __restrict__ b2,
                 ushort_t* __restrict__ aggbf, float* __restrict__ counts) {
    __shared__ ushort_t Xs[64 * XPAD];   // 41,984 B; reused as H (64*HPAD*2 = 33,792 B)
    __shared__ int s_src[64], s_dst[64];

    const int tid = threadIdx.x;
    const int b   = blockIdx.x >> 10;            // 1024 blocks per batch
    const int e0  = (blockIdx.x & 1023) * 64;
    const int wv = tid >> 6, ln = tid & 63;
    const int m32 = ln & 31, half = ln >> 5;
    const int col = wv * 32 + m32;

    // ---- hoisted W1 B-prefetch (covers cold L2 latency under the staging phase) ----
    const ushort_t* b1ph = w1hi + ((size_t)wv * 64 + ln) * 8;
    const ushort_t* b1pl = w1lo + ((size_t)wv * 64 + ln) * 8;
    s16x8 bh0 = *(const s16x8*)b1ph;
    s16x8 bl0 = *(const s16x8*)b1pl;
    s16x8 bh1 = *(const s16x8*)(b1ph + 4096);
    s16x8 bl1 = *(const s16x8*)(b1pl + 4096);

    if (tid < 64) {
        int2 v = ((const int2*)eidx)[(size_t)b * NE + e0 + tid];
        int dv = min(max(v.y, 0), NC - 1);
        s_src[tid] = min(max(v.x, 0), NC - 1);
        s_dst[tid] = dv;
        atomicAdd(&counts[b * NC + dv], 1.0f);   // fused degree count
    }
    __syncthreads();

    // ---- stage X = [src_x | edge_attr] as RNE bf16 ----
    {
        const int row = tid >> 3, c8 = tid & 7;
        const float4* crow = (const float4*)(cell_x + ((size_t)b * NC + s_src[row]) * HID);
        const float4* arow = (const float4*)(eattr + ((size_t)b * NE + e0 + row) * EF);
        #pragma unroll
        for (int i = 0; i < 10; ++i) {
            int c = c8 + i * 8;                  // float4 index 0..79
            float4 v = (c < 64) ? crow[c] : arow[c - 64];
            *(ushort4*)&Xs[row * XPAD + c * 4] =
                make_ushort4(bf16_rne(v.x), bf16_rne(v.y), bf16_rne(v.z), bf16_rne(v.w));
        }
    }
    __syncthreads();

    // ---- GEMM1: hidden = relu(X @ W1 + b1), K=320, 20 k-steps ----
    f32x16 A0, A1;
    {
        float bias = b1[col];
        #pragma unroll
        for (int r = 0; r < 16; ++r) { A0[r] = bias; A1[r] = bias; }
    }
    for (int t = 0; t < 20; t += 2) {
        s16x8 nh = *(const s16x8*)(b1ph + (size_t)min(t + 2, 19) * 4096);
        s16x8 nl = *(const s16x8*)(b1pl + (size_t)min(t + 2, 19) * 4096);
        int ao = m32 * XPAD + t * 16 + half * 8;
        s16x8 a0 = *(const s16x8*)&Xs[ao];
        s16x8 a1 = *(const s16x8*)&Xs[ao + 32 * XPAD];
        A0 = __builtin_amdgcn_mfma_f32_32x32x16_bf16(a0, bh0, A0, 0, 0, 0);
        A0 = __builtin_amdgcn_mfma_f32_32x32x16_bf16(a0, bl0, A0, 0, 0, 0);
        A1 = __builtin_amdgcn_mfma_f32_32x32x16_bf16(a1, bh0, A1, 0, 0, 0);
        A1 = __builtin_amdgcn_mfma_f32_32x32x16_bf16(a1, bl0, A1, 0, 0, 0);
        bh0 = nh; bl0 = nl;
        nh = *(const s16x8*)(b1ph + (size_t)min(t + 3, 19) * 4096);
        nl = *(const s16x8*)(b1pl + (size_t)min(t + 3, 19) * 4096);
        ao = m32 * XPAD + (t + 1) * 16 + half * 8;
        a0 = *(const s16x8*)&Xs[ao];
        a1 = *(const s16x8*)&Xs[ao + 32 * XPAD];
        A0 = __builtin_amdgcn_mfma_f32_32x32x16_bf16(a0, bh1, A0, 0, 0, 0);
        A0 = __builtin_amdgcn_mfma_f32_32x32x16_bf16(a0, bl1, A0, 0, 0, 0);
        A1 = __builtin_amdgcn_mfma_f32_32x32x16_bf16(a1, bh1, A1, 0, 0, 0);
        A1 = __builtin_amdgcn_mfma_f32_32x32x16_bf16(a1, bl1, A1, 0, 0, 0);
        bh1 = nh; bl1 = nl;
    }

    // ---- hoisted W2 B-prefetch (covers cold latency under repack + barrier) ----
    const ushort_t* b2ph = w2hi + ((size_t)wv * 64 + ln) * 8;
    const ushort_t* b2pl = w2lo + ((size_t)wv * 64 + ln) * 8;
    bh0 = *(const s16x8*)b2ph;
    bl0 = *(const s16x8*)b2pl;
    bh1 = *(const s16x8*)(b2ph + 4096);
    bl1 = *(const s16x8*)(b2pl + 4096);

    __syncthreads();   // all X reads done; reuse LDS for H

    // ---- relu + RNE bf16 + store hidden (rows = edges) ----
    #pragma unroll
    for (int r = 0; r < 16; ++r) {
        int row = (r & 3) + 8 * (r >> 2) + 4 * half;
        Xs[row * HPAD + col]        = bf16_rne(fmaxf(A0[r], 0.f));
        Xs[(row + 32) * HPAD + col] = bf16_rne(fmaxf(A1[r], 0.f));
    }
    __syncthreads();

    // ---- GEMM2: msg = hidden @ W2 + b2, K=256, 16 k-steps ----
    f32x16 C0, C1;
    {
        float bias = b2[col];
        #pragma unroll
        for (int r = 0; r < 16; ++r) { C0[r] = bias; C1[r] = bias; }
    }
    for (int t = 0; t < 16; t += 2) {
        s16x8 nh = *(const s16x8*)(b2ph + (size_t)min(t + 2, 15) * 4096);
        s16x8 nl = *(const s16x8*)(b2pl + (size_t)min(t + 2, 15) * 4096);
        int ao = m32 * HPAD + t * 16 + half * 8;
        s16x8 a0 = *(const s16x8*)&Xs[ao];
        s16x8 a1 = *(const s16x8*)&Xs[ao + 32 * HPAD];
        C0 = __builtin_amdgcn_mfma_f32_32x32x16_bf16(a0, bh0, C0, 0, 0, 0);
        C0 = __builtin_amdgcn_mfma_f32_32x32x16_bf16(a0, bl0, C0, 0, 0, 0);
        C1 = __builtin_amdgcn_mfma_f32_32x32x16_bf16(a1, bh0, C1, 0, 0, 0);
        C1 = __builtin_amdgcn_mfma_f32_32x32x16_bf16(a1, bl0, C1, 0, 0, 0);
        bh0 = nh; bl0 = nl;
        nh = *(const s16x8*)(b2ph + (size_t)min(t + 3, 15) * 4096);
        nl = *(const s16x8*)(b2pl + (size_t)min(t + 3, 15) * 4096);
        ao = m32 * HPAD + (t + 1) * 16 + half * 8;
        a0 = *(const s16x8*)&Xs[ao];
        a1 = *(const s16x8*)&Xs[ao + 32 * HPAD];
        C0 = __builtin_amdgcn_mfma_f32_32x32x16_bf16(a0, bh1, C0, 0, 0, 0);
        C0 = __builtin_amdgcn_mfma_f32_32x32x16_bf16(a0, bl1, C0, 0, 0, 0);
        C1 = __builtin_amdgcn_mfma_f32_32x32x16_bf16(a1, bh1, C1, 0, 0, 0);
        C1 = __builtin_amdgcn_mfma_f32_32x32x16_bf16(a1, bl1, C1, 0, 0, 0);
        bh1 = nh; bl1 = nl;
    }

    // ---- packed bf16 scatter-add into aggbf[b, dst, col&~1 .. +1] ----
    const int colbase = col & ~1;
    const bool evenl = (m32 & 1) == 0;
    #pragma unroll
    for (int r = 0; r < 16; ++r) {
        int row = (r & 3) + 8 * (r >> 2) + 4 * half;
        {
            float other = __shfl_xor(C0[r], 1, 64);
            float vlo = evenl ? C0[r] : other;
            float vhi = evenl ? other : C0[r];
            if (evenl == (r < 8)) {
                unsigned pk = ((unsigned)bf16_rne(vhi) << 16) | (unsigned)bf16_rne(vlo);
                ushort_t* addr = aggbf + ((size_t)b * NC + s_dst[row]) * HID + colbase;
                asm volatile("global_atomic_pk_add_bf16 %0, %1, off"
                             :: "v"(addr), "v"(pk) : "memory");
            }
        }
        {
            float other = __shfl_xor(C1[r], 1, 64);
            float vlo = evenl ? C1[r] : other;
            float vhi = evenl ? other : C1[r];
            if (evenl == (r < 8)) {
                unsigned pk = ((unsigned)bf16_rne(vhi) << 16) | (unsigned)bf16_rne(vlo);
                ushort_t* addr = aggbf + ((size_t)b * NC + s_dst[row + 32]) * HID + colbase;
                asm volatile("global_atomic_pk_add_bf16 %0, %1, off"
                             :: "v"(addr), "v"(pk) : "memory");
            }
        }
    }
}

// 32 nodes/block, 512 threads = 8 waves; wave wv owns n-tile wv, 1 m-tile
__global__ __launch_bounds__(512, 6)
void node_kernel(const float* __restrict__ cell_x,
                 const ushort_t* __restrict__ aggbf,
                 const float* __restrict__ counts,
                 const ushort_t* __restrict__ w1hi, const ushort_t* __restrict__ w1lo,
                 const float* __restrict__ b1,
                 const ushort_t* __restrict__ w2hi, const ushort_t* __restrict__ w2lo,
                 const float* __restrict__ b2,
                 const float* __restrict__ gamma, const float* __restrict__ beta,
                 float* __restrict__ out) {
    __shared__ ushort_t Us[32 * UPAD];   // 33,280 B; overlays: H (32*HPAD), hs fp32
    __shared__ float s_inv[32];
    float* hs = (float*)Us;

    const int tid = threadIdx.x;
    const int b   = blockIdx.x >> 7;             // 128 blocks per batch
    const int r0  = (blockIdx.x & 127) * 32;
    const int wv = tid >> 6, ln = tid & 63;
    const int m32 = ln & 31, half = ln >> 5;
    const int col = wv * 32 + m32;

    // hoisted uW1 B-prefetch
    const ushort_t* b1ph = w1hi + ((size_t)wv * 64 + ln) * 8;
    const ushort_t* b1pl = w1lo + ((size_t)wv * 64 + ln) * 8;
    s16x8 bhi = *(const s16x8*)b1ph;
    s16x8 blo = *(const s16x8*)b1pl;

    if (tid < 32) {
        float c = counts[b * NC + r0 + tid];
        s_inv[tid] = 1.0f / fmaxf(c, 1.0f);
    }
    __syncthreads();

    // ---- stage U = [cell_x | aggbf/cnt] as RNE bf16 ----
    {
        const int row = tid >> 4, c8 = tid & 15;
        const float4* crow = (const float4*)(cell_x + ((size_t)b * NC + r0 + row) * HID);
        const ushort4* grow = (const ushort4*)(aggbf + ((size_t)b * NC + r0 + row) * HID);
        float inv = s_inv[row];
        #pragma unroll
        for (int i = 0; i < 8; ++i) {
            int c = c8 + i * 16;                 // 4-elem group index 0..127
            if (c < 64) {
                float4 v = crow[c];
                *(ushort4*)&Us[row * UPAD + c * 4] =
                    make_ushort4(bf16_rne(v.x), bf16_rne(v.y), bf16_rne(v.z), bf16_rne(v.w));
            } else {
                ushort4 g = grow[c - 64];
                *(ushort4*)&Us[row * UPAD + c * 4] =
                    make_ushort4(bf16_rne(bf16_to_f(g.x) * inv),
                                 bf16_rne(bf16_to_f(g.y) * inv),
                                 bf16_rne(bf16_to_f(g.z) * inv),
                                 bf16_rne(bf16_to_f(g.w) * inv));
            }
        }
    }
    __syncthreads();

    // ---- GEMM1: hidden = relu(U @ uW1 + ub1), K=512, 32 k-steps ----
    f32x16 acc;
    {
        float bias = b1[col];
        #pragma unroll
        for (int r = 0; r < 16; ++r) acc[r] = bias;
    }
    #pragma unroll 2
    for (int t = 0; t < 32; ++t) {
        int tn1 = (t + 1 < 32) ? t + 1 : 31;
        s16x8 bhin = *(const s16x8*)(b1ph + (size_t)tn1 * 4096);
        s16x8 blon = *(const s16x8*)(b1pl + (size_t)tn1 * 4096);
        s16x8 a = *(const s16x8*)&Us[m32 * UPAD + t * 16 + half * 8];
        acc = __builtin_amdgcn_mfma_f32_32x32x16_bf16(a, bhi, acc, 0, 0, 0);
        acc = __builtin_amdgcn_mfma_f32_32x32x16_bf16(a, blo, acc, 0, 0, 0);
        bhi = bhin; blo = blon;
    }

    // hoisted uW2 B-prefetch (before repack barrier)
    const ushort_t* b2ph = w2hi + ((size_t)wv * 64 + ln) * 8;
    const ushort_t* b2pl = w2lo + ((size_t)wv * 64 + ln) * 8;
    bhi = *(const s16x8*)b2ph;
    blo = *(const s16x8*)b2pl;

    __syncthreads();   // U dead; reuse for H

    #pragma unroll
    for (int r = 0; r < 16; ++r) {
        int row = (r & 3) + 8 * (r >> 2) + 4 * half;
        Us[row * HPAD + col] = bf16_rne(fmaxf(acc[r], 0.f));
    }
    __syncthreads();

    // ---- GEMM2: o = hidden @ uW2 + ub2, K=256, 16 k-steps ----
    f32x16 c2;
    {
        float bias = b2[col];
        #pragma unroll
        for (int r = 0; r < 16; ++r) c2[r] = bias;
    }
    #pragma unroll 2
    for (int t = 0; t < 16; ++t) {
        int tn1 = (t + 1 < 16) ? t + 1 : 15;
        s16x8 bhin = *(const s16x8*)(b2ph + (size_t)tn1 * 4096);
        s16x8 blon = *(const s16x8*)(b2pl + (size_t)tn1 * 4096);
        s16x8 a = *(const s16x8*)&Us[m32 * HPAD + t * 16 + half * 8];
        c2 = __builtin_amdgcn_mfma_f32_32x32x16_bf16(a, bhi, c2, 0, 0, 0);
        c2 = __builtin_amdgcn_mfma_f32_32x32x16_bf16(a, blo, c2, 0, 0, 0);
        bhi = bhin; blo = blon;
    }
    __syncthreads();   // H dead; reuse pool for hs (fp32)

    // ---- residual: h = cell_x + o ----
    #pragma unroll
    for (int r = 0; r < 16; ++r) {
        int row = (r & 3) + 8 * (r >> 2) + 4 * half;
        float cx = cell_x[((size_t)b * NC + r0 + row) * HID + col];
        hs[row * HSF + col] = c2[r] + cx;
    }
    __syncthreads();

    // ---- LayerNorm per row: wave wv handles rows wv*4..+3 ----
    #pragma unroll
    for (int i = 0; i < 4; ++i) {
        int r = wv * 4 + i;
        float v[4];
        float s = 0.f, q = 0.f;
        #pragma unroll
        for (int j = 0; j < 4; ++j) {
            v[j] = hs[r * HSF + ln + 64 * j];
            s += v[j];
            q = fmaf(v[j], v[j], q);
        }
        #pragma unroll
        for (int off = 32; off > 0; off >>= 1) {
            s += __shfl_xor(s, off, 64);
            q += __shfl_xor(q, off, 64);
        }
        float mu = s * (1.0f / HID);
        float var = q * (1.0f / HID) - mu * mu;
        float rs = rsqrtf(var + EPSV);
        float* orow = out + ((size_t)b * NC + r0 + r) * HID;
        #pragma unroll
        for (int j = 0; j < 4; ++j) {
            int c = ln + 64 * j;
            orow[c] = (v[j] - mu) * rs * gamma[c] + beta[c];
        }
    }
}

extern "C" void kernel_launch(void* const* d_in, const int* in_sizes, int n_in,
                              void* d_out, int out_size, void* d_ws, size_t ws_size,
                              hipStream_t stream) {
    const float* cell_x = (const float*)d_in[0];
    const int*   eidx   = (const int*)d_in[1];
    const float* eattr  = (const float*)d_in[2];
    const float* mW1    = (const float*)d_in[3];
    const float* mb1    = (const float*)d_in[4];
    const float* mW2    = (const float*)d_in[5];
    const float* mb2    = (const float*)d_in[6];
    const float* uW1    = (const float*)d_in[7];
    const float* ub1    = (const float*)d_in[8];
    const float* uW2    = (const float*)d_in[9];
    const float* ub2    = (const float*)d_in[10];
    const float* gamma  = (const float*)d_in[11];
    const float* beta   = (const float*)d_in[12];
    float* out = (float*)d_out;

    ushort_t* aggbf = (ushort_t*)d_ws;                   // [B, NC, HID] bf16 (8 MB)
    float* counts = (float*)(aggbf + (size_t)BSZ * NC * HID);   // [B, NC]
    ushort_t* w1hi = (ushort_t*)(counts + BSZ * NC);     // packed mW1: 320*256
    ushort_t* w1lo = w1hi + KIN * HID;
    ushort_t* w2hi = w1lo + KIN * HID;                   // packed mW2: 256*256
    ushort_t* w2lo = w2hi + HID * HID;
    ushort_t* u1hi = w2lo + HID * HID;                   // packed uW1: 512*256
    ushort_t* u1lo = u1hi + 2 * HID * HID;
    ushort_t* u2hi = u1lo + 2 * HID * HID;               // packed uW2: 256*256
    ushort_t* u2lo = u2hi + HID * HID;

    // zero aggbf (bf16) + counts (fp32): bytes = B*NC*HID*2 + B*NC*4
    int n4 = (BSZ * NC * HID * 2 + BSZ * NC * 4) / 16;
    prep_kernel<<<PACKB + ZEROB, 256, 0, stream>>>(
        mW1, mW2, uW1, uW2, w1hi, w1lo, w2hi, w2lo, u1hi, u1lo, u2hi, u2lo,
        (float4*)d_ws, n4);
    edge_kernel<<<BSZ * NE / 64, 512, 0, stream>>>(cell_x, eidx, eattr,
                                                   w1hi, w1lo, mb1, w2hi, w2lo, mb2,
                                                   aggbf, counts);
    node_kernel<<<BSZ * NC / 32, 512, 0, stream>>>(cell_x, aggbf, counts,
                                                   u1hi, u1lo, ub1, u2hi, u2lo, ub2,
                                                   gamma, beta, out);
}